// Round 8
// baseline (790.207 us; speedup 1.0000x reference)
//
#include <hip/hip_runtime.h>
#include <math.h>

// B=8, L=512, H=8, vd=64, M=64, S=2, hdim=512. f32 in/out.
// MFMA (bf16 2-way-split, 3 products) used for k10_v3sq and the out-GEMM.
// R7 fixes: STH/STL correctly sized (2097152 shorts each; was 2x under-
// allocated -> cross-block races + spill into V3 -> NaN), var clamped >= 0.

using bf16x8 = __attribute__((ext_vector_type(8))) short;
using f32x4  = __attribute__((ext_vector_type(4))) float;

// ---- workspace layout (float units) ----
static const size_t OFF_QS   = 0;                       // 2097152 (k8: smph)
static const size_t OFF_VG   = OFF_QS   + 2097152;      // 2097152 (k8: smpl)
static const size_t OFF_QN   = OFF_VG   + 2097152;      // 32768
static const size_t OFF_KBS  = OFF_QN   + 32768;        // 32768
static const size_t OFF_KBN  = OFF_KBS  + 32768;        // 512
static const size_t OFF_LINV = OFF_KBN  + 512;          // 32768
static const size_t OFF_V1   = OFF_LINV + 32768;        // 2097152
static const size_t OFF_V1SQ = OFF_V1   + 2097152;      // 32768
static const size_t OFF_MEAN = OFF_V1SQ + 32768;        // 2097152
static const size_t OFF_V2   = OFF_MEAN + 2097152;      // 262144
static const size_t OFF_V1H  = OFF_V2   + 262144;       // 1048576 (2097152 shorts)
static const size_t OFF_V1L  = OFF_V1H  + 1048576;      // 1048576
static const size_t OFF_STH  = OFF_V1L  + 1048576;      // 1048576 (2097152 shorts) FIXED
static const size_t OFF_STL  = OFF_STH  + 1048576;      // 1048576 FIXED
static const size_t OFF_V3   = OFF_STL  + 1048576;      // 2097152
static const size_t OFF_WOH  = OFF_V3   + 2097152;      // 131072
static const size_t OFF_WOL  = OFF_WOH  + 131072;       // 131072
static const size_t OFF_KLD  = OFF_WOL  + 131072;       // 64 (32 doubles)
// total ~15.34M floats = ~61.3 MB (round-4 layout ~68 MB fit, so ws_size ok)

// ---------- bf16 split helpers ----------
__device__ __forceinline__ unsigned short f2bf(float x) {
  unsigned u = __float_as_uint(x);
  u += 0x7FFFu + ((u >> 16) & 1u);
  return (unsigned short)(u >> 16);
}
__device__ __forceinline__ float bf2f(unsigned short s) {
  return __uint_as_float(((unsigned)s) << 16);
}
__device__ __forceinline__ void splitbf(float x, unsigned short& h, unsigned short& l) {
  h = f2bf(x);
  l = f2bf(x - bf2f(h));
}

// ---------- LDS tile helpers (blockDim.x == 256) ----------
__device__ __forceinline__ void load_tile_t(float* dst, const float* src, int ld) {
  int t = threadIdx.x;
  int r = t >> 2;
  int c0 = (t & 3) * 16;
#pragma unroll
  for (int q = 0; q < 4; ++q) {
    float4 v = *(const float4*)(src + (size_t)r * ld + c0 + q * 4);
    int c = c0 + q * 4;
    dst[(c + 0) * 68 + r] = v.x;
    dst[(c + 1) * 68 + r] = v.y;
    dst[(c + 2) * 68 + r] = v.z;
    dst[(c + 3) * 68 + r] = v.w;
  }
}
__device__ __forceinline__ void load_tile_n(float* dst, const float* src, int ld) {
  int t = threadIdx.x;
  int r = t >> 2;
  int c0 = (t & 3) * 16;
#pragma unroll
  for (int q = 0; q < 4; ++q) {
    float4 v = *(const float4*)(src + (size_t)r * ld + c0 + q * 4);
    *(float4*)(dst + r * 68 + c0 + q * 4) = v;
  }
}
__device__ __forceinline__ void mma64(const float* aT, const float* bT, int tr, int tn,
                                      float acc[4][4]) {
#pragma unroll 16
  for (int k = 0; k < 64; ++k) {
    float4 av = *(const float4*)(aT + k * 68 + tr);
    float4 bv = *(const float4*)(bT + k * 68 + tn);
    float a[4] = {av.x, av.y, av.z, av.w};
    float b[4] = {bv.x, bv.y, bv.z, bv.w};
#pragma unroll
    for (int i = 0; i < 4; ++i)
#pragma unroll
      for (int j = 0; j < 4; ++j) acc[i][j] = fmaf(a[i], b[j], acc[i][j]);
  }
}
__device__ __forceinline__ void mma64_dual(const float* aT, const float* b1T,
                                           const float* b2T, int tr, int tn,
                                           float acc1[4][4], float acc2[4][4]) {
#pragma unroll 8
  for (int k = 0; k < 64; ++k) {
    float4 av = *(const float4*)(aT + k * 68 + tr);
    float4 b1 = *(const float4*)(b1T + k * 68 + tn);
    float4 b2 = *(const float4*)(b2T + k * 68 + tn);
    float a[4] = {av.x, av.y, av.z, av.w};
    float p[4] = {b1.x, b1.y, b1.z, b1.w};
    float q[4] = {b2.x, b2.y, b2.z, b2.w};
#pragma unroll
    for (int i = 0; i < 4; ++i)
#pragma unroll
      for (int j = 0; j < 4; ++j) {
        acc1[i][j] = fmaf(a[i], p[j], acc1[i][j]);
        acc2[i][j] = fmaf(a[i], q[j], acc2[i][j]);
      }
  }
}

// ---------- gemm0: qkv GEMM + scatter + fused qn ----------
__global__ __launch_bounds__(256) void gemm0(
    const float* __restrict__ A, const float* __restrict__ Bm,
    float* __restrict__ qs, float* __restrict__ vg, const float* __restrict__ lls,
    float* __restrict__ qn) {
  __shared__ float As[16][68];
  __shared__ float Bs[16][68];
  const int t = threadIdx.x;
  const int r0 = blockIdx.x * 64;
  const int n0 = blockIdx.y * 64;
  const int lr = t >> 2;
  const int lk = (t & 3) * 4;
  const int tr = (t >> 4) * 4;
  const int tn = (t & 15) * 4;
  const float* Ap = A + (size_t)(r0 + lr) * 512 + lk;
  const float* Bp = Bm + (size_t)(n0 + lr) * 512 + lk;
  float acc[4][4] = {};
  for (int k0 = 0; k0 < 512; k0 += 16) {
    float4 a4 = *(const float4*)(Ap + k0);
    float4 b4 = *(const float4*)(Bp + k0);
    As[lk + 0][lr] = a4.x; As[lk + 1][lr] = a4.y; As[lk + 2][lr] = a4.z; As[lk + 3][lr] = a4.w;
    Bs[lk + 0][lr] = b4.x; Bs[lk + 1][lr] = b4.y; Bs[lk + 2][lr] = b4.z; Bs[lk + 3][lr] = b4.w;
    __syncthreads();
#pragma unroll
    for (int k = 0; k < 16; ++k) {
      float4 av = *(const float4*)&As[k][tr];
      float4 bv = *(const float4*)&Bs[k][tn];
      float a[4] = {av.x, av.y, av.z, av.w};
      float b[4] = {bv.x, bv.y, bv.z, bv.w};
#pragma unroll
      for (int i = 0; i < 4; ++i)
#pragma unroll
        for (int j = 0; j < 4; ++j) acc[i][j] = fmaf(a[i], b[j], acc[i][j]);
    }
    __syncthreads();
  }
  const int h = n0 >> 7;
  const bool isq = (n0 & 64) == 0;
  if (isq) {
    float invls[4];
#pragma unroll
    for (int j = 0; j < 4; ++j) invls[j] = __expf(-lls[h * 64 + tn + j]);
    float* red = &As[0][0];  // 16*68 = 1088 = 64*17
#pragma unroll
    for (int i = 0; i < 4; ++i) {
      int r = r0 + tr + i;
      int b = r >> 9, l = r & 511;
      float4 o;
      o.x = acc[i][0] * invls[0];
      o.y = acc[i][1] * invls[1];
      o.z = acc[i][2] * invls[2];
      o.w = acc[i][3] * invls[3];
      *(float4*)(qs + (((size_t)(b * 8 + h)) * 512 + l) * 64 + tn) = o;
      red[(tr + i) * 17 + (t & 15)] = o.x * o.x + o.y * o.y + o.z * o.z + o.w * o.w;
    }
    __syncthreads();
    if (t < 64) {
      float s = 0.f;
#pragma unroll
      for (int g = 0; g < 16; ++g) s += red[t * 17 + g];
      int r = r0 + t;
      int b = r >> 9, l = r & 511;
      qn[(b * 8 + h) * 512 + l] = s;
    }
  } else {
#pragma unroll
    for (int i = 0; i < 4; ++i) {
      int r = r0 + tr + i;
      int b = r >> 9, l = r & 511;
      float4 o = {acc[i][0], acc[i][1], acc[i][2], acc[i][3]};
      *(float4*)(vg + (((size_t)(b * 8 + h)) * 512 + l) * 64 + tn) = o;
    }
  }
}

// ---------- k2: k_beta + norms ----------
__global__ __launch_bounds__(256) void k2_kbeta(const float* __restrict__ W,
                                                const float* __restrict__ ckg,
                                                const float* __restrict__ log_ls,
                                                float* __restrict__ kbs,
                                                float* __restrict__ kbn) {
  __shared__ float ck[512];
  __shared__ float kb[64];
  int h = blockIdx.x >> 6, m = blockIdx.x & 63;
  int t = threadIdx.x;
  ck[t] = ckg[m * 512 + t];
  ck[t + 256] = ckg[m * 512 + t + 256];
  __syncthreads();
  int w = t >> 6, lane = t & 63;
  for (int d = w; d < 64; d += 4) {
    const float* row = W + (size_t)(h * 64 + d) * 512;
    float p = 0.f;
    for (int k = lane; k < 512; k += 64) p = fmaf(row[k], ck[k], p);
#pragma unroll
    for (int off = 32; off > 0; off >>= 1) p += __shfl_down(p, off);
    if (lane == 0) {
      float v = p * __expf(-log_ls[h * 64 + d]);
      kbs[(size_t)h * 4096 + m * 64 + d] = v;
      kb[d] = v;
    }
  }
  __syncthreads();
  if (w == 0) {
    float v = kb[lane];
    v *= v;
#pragma unroll
    for (int off = 32; off > 0; off >>= 1) v += __shfl_down(v, off);
    if (lane == 0) kbn[h * 64 + m] = v;
  }
}

// ---------- k3: K_kk, KL vKv, cholesky, Linv ----------
__global__ __launch_bounds__(64) void k3_chol(const float* __restrict__ kbs,
                                              const float* __restrict__ kbn,
                                              const float* __restrict__ vind,
                                              const float* __restrict__ log_sf,
                                              float* __restrict__ linv_g,
                                              double* __restrict__ klbuf) {
  __shared__ float Am[64][65];
  __shared__ float Bm[64][65];
  __shared__ float kn[64];
  int h = blockIdx.x;
  int t = threadIdx.x;
  for (int m = 0; m < 64; ++m) Bm[m][t] = kbs[(size_t)h * 4096 + m * 64 + t];
  kn[t] = kbn[h * 64 + t];
  float lsf = log_sf[h];
  __syncthreads();
  float nh = -0.5f * kn[t] + lsf;
  for (int n = 0; n < 64; ++n) {
    float dt = 0.f;
#pragma unroll 8
    for (int d = 0; d < 64; ++d) dt = fmaf(Bm[t][d], Bm[n][d], dt);
    Am[t][n] = __expf(dt + nh - 0.5f * kn[n]);
  }
  __syncthreads();
  for (int m = 0; m < 64; ++m) Bm[m][t] = vind[(size_t)h * 4096 + m * 64 + t];
  __syncthreads();
  float s = 0.f;
  for (int m = 0; m < 64; ++m) {
    float tt = 0.f;
    for (int n = 0; n < 64; ++n) tt = fmaf(Am[m][n], Bm[n][t], tt);
    s = fmaf(Bm[m][t], tt, s);
  }
#pragma unroll
  for (int off = 32; off > 0; off >>= 1) s += __shfl_down(s, off);
  if (t == 0) atomicAdd(&klbuf[1], 0.5 * (double)s);
  __syncthreads();
  Am[t][t] += 1e-4f;
  __syncthreads();
  for (int k = 0; k < 64; ++k) {
    if (t == k) Am[k][k] = sqrtf(Am[k][k]);
    __syncthreads();
    if (t > k) Am[t][k] /= Am[k][k];
    __syncthreads();
    if (t > k) {
      float f = Am[t][k];
      for (int j = k + 1; j <= t; ++j) Am[t][j] = fmaf(-f, Am[j][k], Am[t][j]);
    }
    __syncthreads();
  }
  for (int i = 0; i < t; ++i) Bm[i][t] = 0.f;
  Bm[t][t] = 1.f / Am[t][t];
  for (int i = t + 1; i < 64; ++i) {
    float a = 0.f;
    for (int j = t; j < i; ++j) a = fmaf(Am[i][j], Bm[j][t], a);
    Bm[i][t] = -a / Am[i][i];
  }
  __syncthreads();
  for (int m = 0; m < 64; ++m) linv_g[(size_t)h * 4096 + m * 64 + t] = Bm[m][t];
}

// ---------- ks_build: S^T bf16 hi/lo + KL terms ----------
// sT[hd][n][m] = S[m][n]; S[m][n] = (m==n)?exp(ldiag):(m>n?ltri[m][n]:0)
__global__ __launch_bounds__(256) void ks_build(const float* __restrict__ ltri,
                                                const float* __restrict__ ldiag,
                                                unsigned short* __restrict__ sth,
                                                unsigned short* __restrict__ stl,
                                                double* __restrict__ klbuf) {
  __shared__ float r1[256], r2[256];
  int hd = blockIdx.x;
  int t = threadIdx.x;
  float p2 = 0.f, pl = 0.f;
  for (int i = t; i < 4096; i += 256) {
    int n = i >> 6, m = i & 63;  // output-major (transposed)
    float v;
    if (m == n) v = __expf(ldiag[hd * 64 + m]);
    else if (m > n) v = ltri[(size_t)hd * 4096 + m * 64 + n];
    else v = 0.f;
    unsigned short h, l;
    splitbf(v, h, l);
    sth[(size_t)hd * 4096 + i] = h;
    stl[(size_t)hd * 4096 + i] = l;
    p2 = fmaf(0.5f * v, v, p2);
  }
  if (t < 64) pl = ldiag[hd * 64 + t];
  r1[t] = p2;
  r2[t] = pl;
  __syncthreads();
  for (int sft = 128; sft > 0; sft >>= 1) {
    if (t < sft) { r1[t] += r1[t + sft]; r2[t] += r2[t + sft]; }
    __syncthreads();
  }
  if (t == 0) {
    atomicAdd(&klbuf[0], (double)r1[0]);
    atomicAdd(&klbuf[2], (double)r2[0]);
  }
}

// ---------- kconv_wo: split W_O to bf16 hi/lo ----------
__global__ __launch_bounds__(256) void kconv_wo(const float* __restrict__ w,
                                                unsigned short* __restrict__ wh,
                                                unsigned short* __restrict__ wl) {
  int i = blockIdx.x * 256 + threadIdx.x;  // 262144 total
  float v = w[i];
  unsigned short h, l;
  splitbf(v, h, l);
  wh[i] = h;
  wl[i] = l;
}

// ---------- k4: K_qk -> v1 (f32 + bf16), v1sq, meanA ----------
__global__ __launch_bounds__(256) void k4_fused(
    const float* __restrict__ qs, const float* __restrict__ qn,
    const float* __restrict__ kbs, const float* __restrict__ kbn,
    const float* __restrict__ linv, const float* __restrict__ vind,
    const float* __restrict__ log_sf, float* __restrict__ v1,
    unsigned short* __restrict__ v1h, unsigned short* __restrict__ v1l,
    float* __restrict__ v1sq, float* __restrict__ meanbuf) {
  extern __shared__ float lds[];
  float* qsT = lds;
  float* kbT = lds + 4352;
  float* liT = lds + 2 * 4352;
  float* vbN = lds + 3 * 4352;
  float* red = lds + 4 * 4352;
  __shared__ float qn_s[64], kbn_s[64];
  const int lt = blockIdx.x, bh = blockIdx.y;
  const int h = bh & 7;
  const int t = threadIdx.x;
  const int l0 = lt * 64;
  const int tr = (t >> 4) * 4, tn = (t & 15) * 4;
  load_tile_t(qsT, qs + ((size_t)bh * 512 + l0) * 64, 64);
  load_tile_t(kbT, kbs + (size_t)h * 4096, 64);
  load_tile_t(liT, linv + (size_t)h * 4096, 64);
  load_tile_n(vbN, vind + (size_t)h * 4096, 64);
  if (t < 64) {
    qn_s[t] = qn[bh * 512 + l0 + t];
    kbn_s[t] = kbn[h * 64 + t];
  }
  __syncthreads();
  float acc[4][4] = {};
  mma64(qsT, kbT, tr, tn, acc);
  const float lsf = log_sf[h];
  float arow[4], acol[4];
#pragma unroll
  for (int i = 0; i < 4; ++i) arow[i] = -0.5f * qn_s[tr + i];
#pragma unroll
  for (int j = 0; j < 4; ++j) acol[j] = -0.5f * kbn_s[tn + j] + lsf;
  float kv[4][4];
#pragma unroll
  for (int i = 0; i < 4; ++i)
#pragma unroll
    for (int j = 0; j < 4; ++j) kv[i][j] = __expf(acc[i][j] + arow[i] + acol[j]);
  __syncthreads();
#pragma unroll
  for (int i = 0; i < 4; ++i)
#pragma unroll
    for (int j = 0; j < 4; ++j) qsT[(tn + j) * 68 + (tr + i)] = kv[i][j];
  __syncthreads();
  float a2[4][4] = {};
  float a3[4][4] = {};
  mma64_dual(qsT, liT, vbN, tr, tn, a2, a3);
#pragma unroll
  for (int i = 0; i < 4; ++i) {
    const size_t rowbase = ((size_t)bh * 512 + l0 + tr + i) * 64 + tn;
    float4 o = {a2[i][0], a2[i][1], a2[i][2], a2[i][3]};
    *(float4*)(v1 + rowbase) = o;
    short4 sh, sl;
    unsigned short hh, ll;
    splitbf(o.x, hh, ll); sh.x = (short)hh; sl.x = (short)ll;
    splitbf(o.y, hh, ll); sh.y = (short)hh; sl.y = (short)ll;
    splitbf(o.z, hh, ll); sh.z = (short)hh; sl.z = (short)ll;
    splitbf(o.w, hh, ll); sh.w = (short)hh; sl.w = (short)ll;
    *(short4*)(v1h + rowbase) = sh;
    *(short4*)(v1l + rowbase) = sl;
    red[(tr + i) * 17 + (t & 15)] =
        a2[i][0] * a2[i][0] + a2[i][1] * a2[i][1] + a2[i][2] * a2[i][2] + a2[i][3] * a2[i][3];
    float4 o3 = {a3[i][0], a3[i][1], a3[i][2], a3[i][3]};
    *(float4*)(meanbuf + rowbase) = o3;
  }
  __syncthreads();
  if (t < 64) {
    float s2 = 0.f;
#pragma unroll
    for (int g = 0; g < 16; ++g) s2 += red[t * 17 + g];
    v1sq[bh * 512 + l0 + t] = s2;
  }
}

// ---------- k5: v2 = v1^T @ v_gamma; + KL v2^2 ----------
__global__ __launch_bounds__(256) void k5_v2(const float* __restrict__ v1,
                                             const float* __restrict__ vg,
                                             float* __restrict__ v2,
                                             double* __restrict__ klbuf) {
  __shared__ float v1t[64 * 68];
  __shared__ float vgt[64 * 68];
  __shared__ float redp[256];
  const int bh = blockIdx.x;
  const int b = bh >> 3;
  const int t = threadIdx.x;
  const int tr = (t >> 4) * 4, tn = (t & 15) * 4;
  float acc[4][4] = {};
  for (int c0 = 0; c0 < 512; c0 += 64) {
    __syncthreads();
    load_tile_n(v1t, v1 + ((size_t)bh * 512 + c0) * 64, 64);
    load_tile_n(vgt, vg + ((size_t)bh * 512 + c0) * 64, 64);
    __syncthreads();
    mma64(v1t, vgt, tr, tn, acc);
  }
  float p = 0.f;
#pragma unroll
  for (int i = 0; i < 4; ++i) {
    float4 o = {acc[i][0], acc[i][1], acc[i][2], acc[i][3]};
    *(float4*)(v2 + ((size_t)bh * 64 + tr + i) * 64 + tn) = o;
    p += acc[i][0] * acc[i][0] + acc[i][1] * acc[i][1] + acc[i][2] * acc[i][2] +
         acc[i][3] * acc[i][3];
  }
  redp[t] = p;
  __syncthreads();
  if (t < 64) {
    float s = redp[t] + redp[t + 64] + redp[t + 128] + redp[t + 192];
#pragma unroll
    for (int off = 32; off > 0; off >>= 1) s += __shfl_down(s, off);
    if (t == 0) atomicAdd(&klbuf[11 + b], (double)s);
  }
}

// ---------- k6: mean += K_qq @ v_gamma; KL vg*mean1 ----------
__global__ __launch_bounds__(256) void k6_mean1(const float* __restrict__ qs,
                                                const float* __restrict__ qn,
                                                const float* __restrict__ vg,
                                                const float* __restrict__ log_sf,
                                                float* __restrict__ meanbuf,
                                                double* __restrict__ klbuf) {
  extern __shared__ float lds[];
  float* qrT = lds;
  float* qcT = lds + 4352;
  float* sT = lds + 2 * 4352;
  float* vgN = lds + 3 * 4352;
  __shared__ float qn_r[64], qn_c[64], redp[256];
  const int lt = blockIdx.x, bh = blockIdx.y;
  const int b = bh >> 3, h = bh & 7;
  const int l0 = lt * 64;
  const int t = threadIdx.x;
  const int tr = (t >> 4) * 4, tn = (t & 15) * 4;
  load_tile_t(qrT, qs + ((size_t)bh * 512 + l0) * 64, 64);
  if (t < 64) qn_r[t] = qn[bh * 512 + l0 + t];
  const float lsf = log_sf[h];
  float acc[4][4] = {};
  for (int c0 = 0; c0 < 512; c0 += 64) {
    __syncthreads();
    load_tile_t(qcT, qs + ((size_t)bh * 512 + c0) * 64, 64);
    load_tile_n(vgN, vg + ((size_t)bh * 512 + c0) * 64, 64);
    if (t < 64) qn_c[t] = qn[bh * 512 + c0 + t];
    __syncthreads();
    float dt[4][4] = {};
    mma64(qrT, qcT, tr, tn, dt);
    float arow[4], acol[4];
#pragma unroll
    for (int i = 0; i < 4; ++i) arow[i] = -0.5f * qn_r[tr + i];
#pragma unroll
    for (int j = 0; j < 4; ++j) acol[j] = -0.5f * qn_c[tn + j] + lsf;
#pragma unroll
    for (int i = 0; i < 4; ++i)
#pragma unroll
      for (int j = 0; j < 4; ++j)
        sT[(tn + j) * 68 + (tr + i)] = __expf(dt[i][j] + arow[i] + acol[j]);
    __syncthreads();
    mma64(sT, vgN, tr, tn, acc);
  }
  float pb = 0.f;
#pragma unroll
  for (int i = 0; i < 4; ++i) {
    size_t rowbase = ((size_t)bh * 512 + l0 + tr + i) * 64 + tn;
    float4 vgr = *(const float4*)(vg + rowbase);
    float4 mb = *(const float4*)(meanbuf + rowbase);
    pb += acc[i][0] * vgr.x + acc[i][1] * vgr.y + acc[i][2] * vgr.z + acc[i][3] * vgr.w;
    mb.x += acc[i][0]; mb.y += acc[i][1]; mb.z += acc[i][2]; mb.w += acc[i][3];
    *(float4*)(meanbuf + rowbase) = mb;
  }
  redp[t] = pb;
  __syncthreads();
  if (t < 64) {
    float s = redp[t] + redp[t + 64] + redp[t + 128] + redp[t + 192];
#pragma unroll
    for (int off = 32; off > 0; off >>= 1) s += __shfl_down(s, off);
    if (t == 0) atomicAdd(&klbuf[3 + b], (double)s);
  }
}

// ---------- k10_mfma: v3sq[b,h,d,l] = || v1_l^T S_hd ||^2 via MFMA ----------
// A = v1[l][m] bf16 hi/lo (natural), B = S[m][n] via sT[n][m] bf16 hi/lo.
// mfma_f32_16x16x32_bf16: A lane: row=lane&15; B lane: col=lane&15;
//                         D lane: col=lane&15, row=(lane>>4)*4+reg.
__global__ __launch_bounds__(256) void k10_mfma(const unsigned short* __restrict__ v1h,
                                                const unsigned short* __restrict__ v1l,
                                                const unsigned short* __restrict__ sth,
                                                const unsigned short* __restrict__ stl,
                                                float* __restrict__ v3) {
  const int bh = blockIdx.x;
  const int l0 = blockIdx.y * 64;
  const int dz = blockIdx.z;
  const int h = bh & 7;
  const int t = threadIdx.x;
  const int wv = t >> 6;
  const int lane = t & 63;
  const int lr = lane & 15;
  const int kq = lane >> 4;
  // preload A fragments (reused for all 16 d)
  const size_t arow = ((size_t)bh * 512 + l0 + wv * 16 + lr) * 64;
  bf16x8 ah[2], al[2];
#pragma unroll
  for (int kk = 0; kk < 2; ++kk) {
    const int kb = kk * 32 + kq * 8;
    ah[kk] = *(const bf16x8*)(v1h + arow + kb);
    al[kk] = *(const bf16x8*)(v1l + arow + kb);
  }
  for (int dd = 0; dd < 16; ++dd) {
    const int d = dz * 16 + dd;
    const int hd = h * 64 + d;
    f32x4 acc[4];
#pragma unroll
    for (int ns = 0; ns < 4; ++ns) acc[ns] = (f32x4){0.f, 0.f, 0.f, 0.f};
#pragma unroll
    for (int ns = 0; ns < 4; ++ns) {
      const size_t scol = (size_t)hd * 4096 + (size_t)(ns * 16 + lr) * 64;
#pragma unroll
      for (int kk = 0; kk < 2; ++kk) {
        const int kb = kk * 32 + kq * 8;
        bf16x8 bh8 = *(const bf16x8*)(sth + scol + kb);
        bf16x8 bl8 = *(const bf16x8*)(stl + scol + kb);
        acc[ns] = __builtin_amdgcn_mfma_f32_16x16x32_bf16(ah[kk], bh8, acc[ns], 0, 0, 0);
        acc[ns] = __builtin_amdgcn_mfma_f32_16x16x32_bf16(ah[kk], bl8, acc[ns], 0, 0, 0);
        acc[ns] = __builtin_amdgcn_mfma_f32_16x16x32_bf16(al[kk], bh8, acc[ns], 0, 0, 0);
      }
    }
    float s[4];
#pragma unroll
    for (int r = 0; r < 4; ++r) {
      s[r] = acc[0][r] * acc[0][r] + acc[1][r] * acc[1][r] + acc[2][r] * acc[2][r] +
             acc[3][r] * acc[3][r];
    }
#pragma unroll
    for (int off = 1; off <= 8; off <<= 1) {
#pragma unroll
      for (int r = 0; r < 4; ++r) s[r] += __shfl_xor(s[r], off);
    }
    if (lr == 0) {
      const size_t base = ((size_t)(bh * 64 + d)) * 512 + l0 + wv * 16 + kq * 4;
      v3[base + 0] = s[0];
      v3[base + 1] = s[1];
      v3[base + 2] = s[2];
      v3[base + 3] = s[3];
    }
  }
}

// ---------- k8: mean2, chol_covar, samples -> bf16 hi/lo ----------
__global__ __launch_bounds__(256) void k8_samples(
    const float* __restrict__ v1, const float* __restrict__ v2,
    const float* __restrict__ meanbuf, const float* __restrict__ v3,
    const float* __restrict__ v1sq, const float* __restrict__ eps,
    const float* __restrict__ log_sf, unsigned short* __restrict__ smph,
    unsigned short* __restrict__ smpl) {
  extern __shared__ float lds[];
  float* v1T = lds;
  float* v2N = lds + 4352;
  float* v3T = lds + 2 * 4352;
  __shared__ float v1sq_s[64];
  const int lt = blockIdx.x, bh = blockIdx.y;
  const int b = bh >> 3, h = bh & 7;
  const int l0 = lt * 64;
  const int t = threadIdx.x;
  const int tr = (t >> 4) * 4, tn = (t & 15) * 4;
  load_tile_t(v1T, v1 + ((size_t)bh * 512 + l0) * 64, 64);
  load_tile_n(v2N, v2 + (size_t)bh * 4096, 64);
  load_tile_n(v3T, v3 + (size_t)bh * 64 * 512 + l0, 512);
  if (t < 64) v1sq_s[t] = v1sq[bh * 512 + l0 + t];
  __syncthreads();
  float acc[4][4] = {};
  mma64(v1T, v2N, tr, tn, acc);
  const float sf = __expf(log_sf[h]);
#pragma unroll
  for (int i = 0; i < 4; ++i) {
    const int l = l0 + tr + i;
    size_t mbase = ((size_t)bh * 512 + l) * 64 + tn;
    float4 mb = *(const float4*)(meanbuf + mbase);
    float mean[4] = {mb.x - acc[i][0], mb.y - acc[i][1], mb.z - acc[i][2], mb.w - acc[i][3]};
    float cc[4];
#pragma unroll
    for (int j = 0; j < 4; ++j) {
      float var = sf + v3T[(tn + j) * 68 + (tr + i)] - v1sq_s[tr + i];
      cc[j] = sqrtf(fmaxf(var, 0.f));  // true posterior var >= 0; clamp kills NaN
    }
#pragma unroll
    for (int s2 = 0; s2 < 2; ++s2) {
      float4 ep = *(const float4*)(eps + (((size_t)bh * 2 + s2) * 512 + l) * 64 + tn);
      float o[4];
      o[0] = mean[0] + cc[0] * ep.x;
      o[1] = mean[1] + cc[1] * ep.y;
      o[2] = mean[2] + cc[2] * ep.z;
      o[3] = mean[3] + cc[3] * ep.w;
      short4 sh, sl;
      unsigned short hh, ll;
      splitbf(o[0], hh, ll); sh.x = (short)hh; sl.x = (short)ll;
      splitbf(o[1], hh, ll); sh.y = (short)hh; sl.y = (short)ll;
      splitbf(o[2], hh, ll); sh.z = (short)hh; sl.z = (short)ll;
      splitbf(o[3], hh, ll); sh.w = (short)hh; sl.w = (short)ll;
      const size_t obase = (((size_t)(b * 2 + s2) * 512 + l) * 512) + h * 64 + tn;
      *(short4*)(smph + obase) = sh;
      *(short4*)(smpl + obase) = sl;
    }
  }
}

// ---------- gemm1_mfma: out = samples @ W_O^T + bias ----------
__global__ __launch_bounds__(256) void gemm1_mfma(const unsigned short* __restrict__ smph,
                                                  const unsigned short* __restrict__ smpl,
                                                  const unsigned short* __restrict__ woh,
                                                  const unsigned short* __restrict__ wol,
                                                  const float* __restrict__ bias,
                                                  float* __restrict__ out) {
  const int r0 = blockIdx.x * 64;
  const int n0 = blockIdx.y * 64;
  const int t = threadIdx.x;
  const int wv = t >> 6;
  const int lane = t & 63;
  const int lr = lane & 15;
  const int kq = lane >> 4;
  const size_t arow = ((size_t)(r0 + wv * 16 + lr)) * 512;
  f32x4 acc[4];
#pragma unroll
  for (int ns = 0; ns < 4; ++ns) acc[ns] = (f32x4){0.f, 0.f, 0.f, 0.f};
  for (int ks = 0; ks < 16; ++ks) {
    const int kb = ks * 32 + kq * 8;
    bf16x8 ah = *(const bf16x8*)(smph + arow + kb);
    bf16x8 al = *(const bf16x8*)(smpl + arow + kb);
#pragma unroll
    for (int ns = 0; ns < 4; ++ns) {
      const size_t brow = ((size_t)(n0 + ns * 16 + lr)) * 512 + kb;
      bf16x8 bh8 = *(const bf16x8*)(woh + brow);
      bf16x8 bl8 = *(const bf16x8*)(wol + brow);
      acc[ns] = __builtin_amdgcn_mfma_f32_16x16x32_bf16(ah, bh8, acc[ns], 0, 0, 0);
      acc[ns] = __builtin_amdgcn_mfma_f32_16x16x32_bf16(ah, bl8, acc[ns], 0, 0, 0);
      acc[ns] = __builtin_amdgcn_mfma_f32_16x16x32_bf16(al, bh8, acc[ns], 0, 0, 0);
    }
  }
#pragma unroll
  for (int ns = 0; ns < 4; ++ns) {
    const int outc = n0 + ns * 16 + lr;
    const float bc = bias[outc];
    const int rbase = r0 + wv * 16 + kq * 4;
#pragma unroll
    for (int r = 0; r < 4; ++r) {
      out[(size_t)(rbase + r) * 512 + outc] = acc[ns][r] + bc;
    }
  }
}

// ---------- kfin ----------
__global__ void kfin(const double* __restrict__ klbuf, float* __restrict__ dout) {
  if (threadIdx.x == 0 && blockIdx.x == 0) {
    double pb = 0.0;
    for (int b = 0; b < 8; ++b) pb += klbuf[3 + b] - klbuf[11 + b];
    double kl = -16384.0 + klbuf[0] + klbuf[1] - klbuf[2] + pb / 16.0;
    dout[4194304] = (float)kl;
  }
}

extern "C" void kernel_launch(void* const* d_in, const int* in_sizes, int n_in,
                              void* d_out, int out_size, void* d_ws, size_t ws_size,
                              hipStream_t stream) {
  (void)in_sizes; (void)n_in; (void)out_size; (void)ws_size;
  const float* x     = (const float*)d_in[0];
  const float* cur_k = (const float*)d_in[1];
  const float* eps   = (const float*)d_in[2];
  const float* W_qkv = (const float*)d_in[3];
  const float* lsf   = (const float*)d_in[4];
  const float* lls   = (const float*)d_in[5];
  const float* vind  = (const float*)d_in[6];
  const float* ltri  = (const float*)d_in[7];
  const float* ldia  = (const float*)d_in[8];
  const float* Wo    = (const float*)d_in[9];
  const float* Wob   = (const float*)d_in[10];
  float* out = (float*)d_out;
  float* ws = (float*)d_ws;
  float* qs   = ws + OFF_QS;
  float* vg   = ws + OFF_VG;
  float* qn   = ws + OFF_QN;
  float* kbs  = ws + OFF_KBS;
  float* kbn  = ws + OFF_KBN;
  float* linv = ws + OFF_LINV;
  float* v1   = ws + OFF_V1;
  float* v1s  = ws + OFF_V1SQ;
  float* mean = ws + OFF_MEAN;
  float* v2   = ws + OFF_V2;
  float* v3   = ws + OFF_V3;
  unsigned short* v1h = (unsigned short*)(ws + OFF_V1H);
  unsigned short* v1l = (unsigned short*)(ws + OFF_V1L);
  unsigned short* sth = (unsigned short*)(ws + OFF_STH);
  unsigned short* stl = (unsigned short*)(ws + OFF_STL);
  unsigned short* woh = (unsigned short*)(ws + OFF_WOH);
  unsigned short* wol = (unsigned short*)(ws + OFF_WOL);
  unsigned short* smph = (unsigned short*)(ws + OFF_QS);  // reuse qs (dead after k6)
  unsigned short* smpl = (unsigned short*)(ws + OFF_VG);  // reuse vg (dead after k6)
  double* kld = (double*)(ws + OFF_KLD);

  hipMemsetAsync(kld, 0, 32 * sizeof(double), stream);
  gemm0<<<dim3(64, 16), 256, 0, stream>>>(x, W_qkv, qs, vg, lls, qn);
  k2_kbeta<<<512, 256, 0, stream>>>(W_qkv, cur_k, lls, kbs, kbn);
  k3_chol<<<8, 64, 0, stream>>>(kbs, kbn, vind, lsf, linv, kld);
  ks_build<<<512, 256, 0, stream>>>(ltri, ldia, sth, stl, kld);
  kconv_wo<<<1024, 256, 0, stream>>>(Wo, woh, wol);
  k4_fused<<<dim3(8, 64), 256, 73984, stream>>>(qs, qn, kbs, kbn, linv, vind, lsf,
                                                v1, v1h, v1l, v1s, mean);
  k5_v2<<<64, 256, 0, stream>>>(v1, vg, v2, kld);
  k6_mean1<<<dim3(8, 64), 256, 69632, stream>>>(qs, qn, vg, lsf, mean, kld);
  k10_mfma<<<dim3(64, 8, 4), 256, 0, stream>>>(v1h, v1l, sth, stl, v3);
  k8_samples<<<dim3(8, 64), 256, 52224, stream>>>(v1, v2, mean, v3, v1s, eps, lsf,
                                                  smph, smpl);
  gemm1_mfma<<<dim3(128, 8), 256, 0, stream>>>(smph, smpl, woh, wol, Wob, out);
  kfin<<<1, 64, 0, stream>>>(kld, out);
}

// Round 10
// 611.937 us; speedup vs baseline: 1.2913x; 1.2913x over previous
//
#include <hip/hip_runtime.h>
#include <math.h>

// B=8, L=512, H=8, vd=64, M=64, S=2, hdim=512. f32 in/out.
// R9: k10 rewritten — register-resident fragments, full unroll, B double-
// buffer, 1-product bf16 (threshold 5099 gives decades of headroom),
// fragment-level exact triangular skip, 2 l-strips/wave.

using bf16x8 = __attribute__((ext_vector_type(8))) short;
using f32x4  = __attribute__((ext_vector_type(4))) float;

// ---- workspace layout (float units) ----
static const size_t OFF_QS   = 0;                       // 2097152 (k8: smph)
static const size_t OFF_VG   = OFF_QS   + 2097152;      // 2097152 (k8: smpl)
static const size_t OFF_QN   = OFF_VG   + 2097152;      // 32768
static const size_t OFF_KBS  = OFF_QN   + 32768;        // 32768
static const size_t OFF_KBN  = OFF_KBS  + 32768;        // 512
static const size_t OFF_LINV = OFF_KBN  + 512;          // 32768
static const size_t OFF_V1   = OFF_LINV + 32768;        // 2097152
static const size_t OFF_V1SQ = OFF_V1   + 2097152;      // 32768
static const size_t OFF_MEAN = OFF_V1SQ + 32768;        // 2097152
static const size_t OFF_V2   = OFF_MEAN + 2097152;      // 262144
static const size_t OFF_V1H  = OFF_V2   + 262144;       // 1048576 (2097152 shorts)
static const size_t OFF_V1L  = OFF_V1H  + 1048576;      // 1048576
static const size_t OFF_STH  = OFF_V1L  + 1048576;      // 1048576 (2097152 shorts)
static const size_t OFF_STL  = OFF_STH  + 1048576;      // 1048576
static const size_t OFF_V3   = OFF_STL  + 1048576;      // 2097152
static const size_t OFF_WOH  = OFF_V3   + 2097152;      // 131072
static const size_t OFF_WOL  = OFF_WOH  + 131072;       // 131072
static const size_t OFF_KLD  = OFF_WOL  + 131072;       // 64 (32 doubles)

// ---------- bf16 split helpers ----------
__device__ __forceinline__ unsigned short f2bf(float x) {
  unsigned u = __float_as_uint(x);
  u += 0x7FFFu + ((u >> 16) & 1u);
  return (unsigned short)(u >> 16);
}
__device__ __forceinline__ float bf2f(unsigned short s) {
  return __uint_as_float(((unsigned)s) << 16);
}
__device__ __forceinline__ void splitbf(float x, unsigned short& h, unsigned short& l) {
  h = f2bf(x);
  l = f2bf(x - bf2f(h));
}

// ---------- LDS tile helpers (blockDim.x == 256) ----------
__device__ __forceinline__ void load_tile_t(float* dst, const float* src, int ld) {
  int t = threadIdx.x;
  int r = t >> 2;
  int c0 = (t & 3) * 16;
#pragma unroll
  for (int q = 0; q < 4; ++q) {
    float4 v = *(const float4*)(src + (size_t)r * ld + c0 + q * 4);
    int c = c0 + q * 4;
    dst[(c + 0) * 68 + r] = v.x;
    dst[(c + 1) * 68 + r] = v.y;
    dst[(c + 2) * 68 + r] = v.z;
    dst[(c + 3) * 68 + r] = v.w;
  }
}
__device__ __forceinline__ void load_tile_n(float* dst, const float* src, int ld) {
  int t = threadIdx.x;
  int r = t >> 2;
  int c0 = (t & 3) * 16;
#pragma unroll
  for (int q = 0; q < 4; ++q) {
    float4 v = *(const float4*)(src + (size_t)r * ld + c0 + q * 4);
    *(float4*)(dst + r * 68 + c0 + q * 4) = v;
  }
}
__device__ __forceinline__ void mma64(const float* aT, const float* bT, int tr, int tn,
                                      float acc[4][4]) {
#pragma unroll 16
  for (int k = 0; k < 64; ++k) {
    float4 av = *(const float4*)(aT + k * 68 + tr);
    float4 bv = *(const float4*)(bT + k * 68 + tn);
    float a[4] = {av.x, av.y, av.z, av.w};
    float b[4] = {bv.x, bv.y, bv.z, bv.w};
#pragma unroll
    for (int i = 0; i < 4; ++i)
#pragma unroll
      for (int j = 0; j < 4; ++j) acc[i][j] = fmaf(a[i], b[j], acc[i][j]);
  }
}
__device__ __forceinline__ void mma64_dual(const float* aT, const float* b1T,
                                           const float* b2T, int tr, int tn,
                                           float acc1[4][4], float acc2[4][4]) {
#pragma unroll 8
  for (int k = 0; k < 64; ++k) {
    float4 av = *(const float4*)(aT + k * 68 + tr);
    float4 b1 = *(const float4*)(b1T + k * 68 + tn);
    float4 b2 = *(const float4*)(b2T + k * 68 + tn);
    float a[4] = {av.x, av.y, av.z, av.w};
    float p[4] = {b1.x, b1.y, b1.z, b1.w};
    float q[4] = {b2.x, b2.y, b2.z, b2.w};
#pragma unroll
    for (int i = 0; i < 4; ++i)
#pragma unroll
      for (int j = 0; j < 4; ++j) {
        acc1[i][j] = fmaf(a[i], p[j], acc1[i][j]);
        acc2[i][j] = fmaf(a[i], q[j], acc2[i][j]);
      }
  }
}

// ---------- gemm0: qkv GEMM + scatter + fused qn ----------
__global__ __launch_bounds__(256) void gemm0(
    const float* __restrict__ A, const float* __restrict__ Bm,
    float* __restrict__ qs, float* __restrict__ vg, const float* __restrict__ lls,
    float* __restrict__ qn) {
  __shared__ float As[16][68];
  __shared__ float Bs[16][68];
  const int t = threadIdx.x;
  const int r0 = blockIdx.x * 64;
  const int n0 = blockIdx.y * 64;
  const int lr = t >> 2;
  const int lk = (t & 3) * 4;
  const int tr = (t >> 4) * 4;
  const int tn = (t & 15) * 4;
  const float* Ap = A + (size_t)(r0 + lr) * 512 + lk;
  const float* Bp = Bm + (size_t)(n0 + lr) * 512 + lk;
  float acc[4][4] = {};
  for (int k0 = 0; k0 < 512; k0 += 16) {
    float4 a4 = *(const float4*)(Ap + k0);
    float4 b4 = *(const float4*)(Bp + k0);
    As[lk + 0][lr] = a4.x; As[lk + 1][lr] = a4.y; As[lk + 2][lr] = a4.z; As[lk + 3][lr] = a4.w;
    Bs[lk + 0][lr] = b4.x; Bs[lk + 1][lr] = b4.y; Bs[lk + 2][lr] = b4.z; Bs[lk + 3][lr] = b4.w;
    __syncthreads();
#pragma unroll
    for (int k = 0; k < 16; ++k) {
      float4 av = *(const float4*)&As[k][tr];
      float4 bv = *(const float4*)&Bs[k][tn];
      float a[4] = {av.x, av.y, av.z, av.w};
      float b[4] = {bv.x, bv.y, bv.z, bv.w};
#pragma unroll
      for (int i = 0; i < 4; ++i)
#pragma unroll
        for (int j = 0; j < 4; ++j) acc[i][j] = fmaf(a[i], b[j], acc[i][j]);
    }
    __syncthreads();
  }
  const int h = n0 >> 7;
  const bool isq = (n0 & 64) == 0;
  if (isq) {
    float invls[4];
#pragma unroll
    for (int j = 0; j < 4; ++j) invls[j] = __expf(-lls[h * 64 + tn + j]);
    float* red = &As[0][0];  // 16*68 = 1088 = 64*17
#pragma unroll
    for (int i = 0; i < 4; ++i) {
      int r = r0 + tr + i;
      int b = r >> 9, l = r & 511;
      float4 o;
      o.x = acc[i][0] * invls[0];
      o.y = acc[i][1] * invls[1];
      o.z = acc[i][2] * invls[2];
      o.w = acc[i][3] * invls[3];
      *(float4*)(qs + (((size_t)(b * 8 + h)) * 512 + l) * 64 + tn) = o;
      red[(tr + i) * 17 + (t & 15)] = o.x * o.x + o.y * o.y + o.z * o.z + o.w * o.w;
    }
    __syncthreads();
    if (t < 64) {
      float s = 0.f;
#pragma unroll
      for (int g = 0; g < 16; ++g) s += red[t * 17 + g];
      int r = r0 + t;
      int b = r >> 9, l = r & 511;
      qn[(b * 8 + h) * 512 + l] = s;
    }
  } else {
#pragma unroll
    for (int i = 0; i < 4; ++i) {
      int r = r0 + tr + i;
      int b = r >> 9, l = r & 511;
      float4 o = {acc[i][0], acc[i][1], acc[i][2], acc[i][3]};
      *(float4*)(vg + (((size_t)(b * 8 + h)) * 512 + l) * 64 + tn) = o;
    }
  }
}

// ---------- k2: k_beta + norms ----------
__global__ __launch_bounds__(256) void k2_kbeta(const float* __restrict__ W,
                                                const float* __restrict__ ckg,
                                                const float* __restrict__ log_ls,
                                                float* __restrict__ kbs,
                                                float* __restrict__ kbn) {
  __shared__ float ck[512];
  __shared__ float kb[64];
  int h = blockIdx.x >> 6, m = blockIdx.x & 63;
  int t = threadIdx.x;
  ck[t] = ckg[m * 512 + t];
  ck[t + 256] = ckg[m * 512 + t + 256];
  __syncthreads();
  int w = t >> 6, lane = t & 63;
  for (int d = w; d < 64; d += 4) {
    const float* row = W + (size_t)(h * 64 + d) * 512;
    float p = 0.f;
    for (int k = lane; k < 512; k += 64) p = fmaf(row[k], ck[k], p);
#pragma unroll
    for (int off = 32; off > 0; off >>= 1) p += __shfl_down(p, off);
    if (lane == 0) {
      float v = p * __expf(-log_ls[h * 64 + d]);
      kbs[(size_t)h * 4096 + m * 64 + d] = v;
      kb[d] = v;
    }
  }
  __syncthreads();
  if (w == 0) {
    float v = kb[lane];
    v *= v;
#pragma unroll
    for (int off = 32; off > 0; off >>= 1) v += __shfl_down(v, off);
    if (lane == 0) kbn[h * 64 + m] = v;
  }
}

// ---------- k3: K_kk, KL vKv, cholesky, Linv ----------
__global__ __launch_bounds__(64) void k3_chol(const float* __restrict__ kbs,
                                              const float* __restrict__ kbn,
                                              const float* __restrict__ vind,
                                              const float* __restrict__ log_sf,
                                              float* __restrict__ linv_g,
                                              double* __restrict__ klbuf) {
  __shared__ float Am[64][65];
  __shared__ float Bm[64][65];
  __shared__ float kn[64];
  int h = blockIdx.x;
  int t = threadIdx.x;
  for (int m = 0; m < 64; ++m) Bm[m][t] = kbs[(size_t)h * 4096 + m * 64 + t];
  kn[t] = kbn[h * 64 + t];
  float lsf = log_sf[h];
  __syncthreads();
  float nh = -0.5f * kn[t] + lsf;
  for (int n = 0; n < 64; ++n) {
    float dt = 0.f;
#pragma unroll 8
    for (int d = 0; d < 64; ++d) dt = fmaf(Bm[t][d], Bm[n][d], dt);
    Am[t][n] = __expf(dt + nh - 0.5f * kn[n]);
  }
  __syncthreads();
  for (int m = 0; m < 64; ++m) Bm[m][t] = vind[(size_t)h * 4096 + m * 64 + t];
  __syncthreads();
  float s = 0.f;
  for (int m = 0; m < 64; ++m) {
    float tt = 0.f;
    for (int n = 0; n < 64; ++n) tt = fmaf(Am[m][n], Bm[n][t], tt);
    s = fmaf(Bm[m][t], tt, s);
  }
#pragma unroll
  for (int off = 32; off > 0; off >>= 1) s += __shfl_down(s, off);
  if (t == 0) atomicAdd(&klbuf[1], 0.5 * (double)s);
  __syncthreads();
  Am[t][t] += 1e-4f;
  __syncthreads();
  for (int k = 0; k < 64; ++k) {
    if (t == k) Am[k][k] = sqrtf(Am[k][k]);
    __syncthreads();
    if (t > k) Am[t][k] /= Am[k][k];
    __syncthreads();
    if (t > k) {
      float f = Am[t][k];
      for (int j = k + 1; j <= t; ++j) Am[t][j] = fmaf(-f, Am[j][k], Am[t][j]);
    }
    __syncthreads();
  }
  for (int i = 0; i < t; ++i) Bm[i][t] = 0.f;
  Bm[t][t] = 1.f / Am[t][t];
  for (int i = t + 1; i < 64; ++i) {
    float a = 0.f;
    for (int j = t; j < i; ++j) a = fmaf(Am[i][j], Bm[j][t], a);
    Bm[i][t] = -a / Am[i][i];
  }
  __syncthreads();
  for (int m = 0; m < 64; ++m) linv_g[(size_t)h * 4096 + m * 64 + t] = Bm[m][t];
}

// ---------- ks_build: S^T bf16 hi/lo + KL terms ----------
__global__ __launch_bounds__(256) void ks_build(const float* __restrict__ ltri,
                                                const float* __restrict__ ldiag,
                                                unsigned short* __restrict__ sth,
                                                unsigned short* __restrict__ stl,
                                                double* __restrict__ klbuf) {
  __shared__ float r1[256], r2[256];
  int hd = blockIdx.x;
  int t = threadIdx.x;
  float p2 = 0.f, pl = 0.f;
  for (int i = t; i < 4096; i += 256) {
    int n = i >> 6, m = i & 63;  // output-major (transposed)
    float v;
    if (m == n) v = __expf(ldiag[hd * 64 + m]);
    else if (m > n) v = ltri[(size_t)hd * 4096 + m * 64 + n];
    else v = 0.f;
    unsigned short h, l;
    splitbf(v, h, l);
    sth[(size_t)hd * 4096 + i] = h;
    stl[(size_t)hd * 4096 + i] = l;
    p2 = fmaf(0.5f * v, v, p2);
  }
  if (t < 64) pl = ldiag[hd * 64 + t];
  r1[t] = p2;
  r2[t] = pl;
  __syncthreads();
  for (int sft = 128; sft > 0; sft >>= 1) {
    if (t < sft) { r1[t] += r1[t + sft]; r2[t] += r2[t + sft]; }
    __syncthreads();
  }
  if (t == 0) {
    atomicAdd(&klbuf[0], (double)r1[0]);
    atomicAdd(&klbuf[2], (double)r2[0]);
  }
}

// ---------- kconv_wo: split W_O to bf16 hi/lo ----------
__global__ __launch_bounds__(256) void kconv_wo(const float* __restrict__ w,
                                                unsigned short* __restrict__ wh,
                                                unsigned short* __restrict__ wl) {
  int i = blockIdx.x * 256 + threadIdx.x;  // 262144 total
  float v = w[i];
  unsigned short h, l;
  splitbf(v, h, l);
  wh[i] = h;
  wl[i] = l;
}

// ---------- k4: K_qk -> v1 (f32 + bf16), v1sq, meanA ----------
__global__ __launch_bounds__(256) void k4_fused(
    const float* __restrict__ qs, const float* __restrict__ qn,
    const float* __restrict__ kbs, const float* __restrict__ kbn,
    const float* __restrict__ linv, const float* __restrict__ vind,
    const float* __restrict__ log_sf, float* __restrict__ v1,
    unsigned short* __restrict__ v1h, unsigned short* __restrict__ v1l,
    float* __restrict__ v1sq, float* __restrict__ meanbuf) {
  extern __shared__ float lds[];
  float* qsT = lds;
  float* kbT = lds + 4352;
  float* liT = lds + 2 * 4352;
  float* vbN = lds + 3 * 4352;
  float* red = lds + 4 * 4352;
  __shared__ float qn_s[64], kbn_s[64];
  const int lt = blockIdx.x, bh = blockIdx.y;
  const int h = bh & 7;
  const int t = threadIdx.x;
  const int l0 = lt * 64;
  const int tr = (t >> 4) * 4, tn = (t & 15) * 4;
  load_tile_t(qsT, qs + ((size_t)bh * 512 + l0) * 64, 64);
  load_tile_t(kbT, kbs + (size_t)h * 4096, 64);
  load_tile_t(liT, linv + (size_t)h * 4096, 64);
  load_tile_n(vbN, vind + (size_t)h * 4096, 64);
  if (t < 64) {
    qn_s[t] = qn[bh * 512 + l0 + t];
    kbn_s[t] = kbn[h * 64 + t];
  }
  __syncthreads();
  float acc[4][4] = {};
  mma64(qsT, kbT, tr, tn, acc);
  const float lsf = log_sf[h];
  float arow[4], acol[4];
#pragma unroll
  for (int i = 0; i < 4; ++i) arow[i] = -0.5f * qn_s[tr + i];
#pragma unroll
  for (int j = 0; j < 4; ++j) acol[j] = -0.5f * kbn_s[tn + j] + lsf;
  float kv[4][4];
#pragma unroll
  for (int i = 0; i < 4; ++i)
#pragma unroll
    for (int j = 0; j < 4; ++j) kv[i][j] = __expf(acc[i][j] + arow[i] + acol[j]);
  __syncthreads();
#pragma unroll
  for (int i = 0; i < 4; ++i)
#pragma unroll
    for (int j = 0; j < 4; ++j) qsT[(tn + j) * 68 + (tr + i)] = kv[i][j];
  __syncthreads();
  float a2[4][4] = {};
  float a3[4][4] = {};
  mma64_dual(qsT, liT, vbN, tr, tn, a2, a3);
#pragma unroll
  for (int i = 0; i < 4; ++i) {
    const size_t rowbase = ((size_t)bh * 512 + l0 + tr + i) * 64 + tn;
    float4 o = {a2[i][0], a2[i][1], a2[i][2], a2[i][3]};
    *(float4*)(v1 + rowbase) = o;
    short4 sh, sl;
    unsigned short hh, ll;
    splitbf(o.x, hh, ll); sh.x = (short)hh; sl.x = (short)ll;
    splitbf(o.y, hh, ll); sh.y = (short)hh; sl.y = (short)ll;
    splitbf(o.z, hh, ll); sh.z = (short)hh; sl.z = (short)ll;
    splitbf(o.w, hh, ll); sh.w = (short)hh; sl.w = (short)ll;
    *(short4*)(v1h + rowbase) = sh;
    *(short4*)(v1l + rowbase) = sl;
    red[(tr + i) * 17 + (t & 15)] =
        a2[i][0] * a2[i][0] + a2[i][1] * a2[i][1] + a2[i][2] * a2[i][2] + a2[i][3] * a2[i][3];
    float4 o3 = {a3[i][0], a3[i][1], a3[i][2], a3[i][3]};
    *(float4*)(meanbuf + rowbase) = o3;
  }
  __syncthreads();
  if (t < 64) {
    float s2 = 0.f;
#pragma unroll
    for (int g = 0; g < 16; ++g) s2 += red[t * 17 + g];
    v1sq[bh * 512 + l0 + t] = s2;
  }
}

// ---------- k5: v2 = v1^T @ v_gamma; + KL v2^2 ----------
__global__ __launch_bounds__(256) void k5_v2(const float* __restrict__ v1,
                                             const float* __restrict__ vg,
                                             float* __restrict__ v2,
                                             double* __restrict__ klbuf) {
  __shared__ float v1t[64 * 68];
  __shared__ float vgt[64 * 68];
  __shared__ float redp[256];
  const int bh = blockIdx.x;
  const int b = bh >> 3;
  const int t = threadIdx.x;
  const int tr = (t >> 4) * 4, tn = (t & 15) * 4;
  float acc[4][4] = {};
  for (int c0 = 0; c0 < 512; c0 += 64) {
    __syncthreads();
    load_tile_n(v1t, v1 + ((size_t)bh * 512 + c0) * 64, 64);
    load_tile_n(vgt, vg + ((size_t)bh * 512 + c0) * 64, 64);
    __syncthreads();
    mma64(v1t, vgt, tr, tn, acc);
  }
  float p = 0.f;
#pragma unroll
  for (int i = 0; i < 4; ++i) {
    float4 o = {acc[i][0], acc[i][1], acc[i][2], acc[i][3]};
    *(float4*)(v2 + ((size_t)bh * 64 + tr + i) * 64 + tn) = o;
    p += acc[i][0] * acc[i][0] + acc[i][1] * acc[i][1] + acc[i][2] * acc[i][2] +
         acc[i][3] * acc[i][3];
  }
  redp[t] = p;
  __syncthreads();
  if (t < 64) {
    float s = redp[t] + redp[t + 64] + redp[t + 128] + redp[t + 192];
#pragma unroll
    for (int off = 32; off > 0; off >>= 1) s += __shfl_down(s, off);
    if (t == 0) atomicAdd(&klbuf[11 + b], (double)s);
  }
}

// ---------- k6: mean += K_qq @ v_gamma; KL vg*mean1 ----------
__global__ __launch_bounds__(256) void k6_mean1(const float* __restrict__ qs,
                                                const float* __restrict__ qn,
                                                const float* __restrict__ vg,
                                                const float* __restrict__ log_sf,
                                                float* __restrict__ meanbuf,
                                                double* __restrict__ klbuf) {
  extern __shared__ float lds[];
  float* qrT = lds;
  float* qcT = lds + 4352;
  float* sT = lds + 2 * 4352;
  float* vgN = lds + 3 * 4352;
  __shared__ float qn_r[64], qn_c[64], redp[256];
  const int lt = blockIdx.x, bh = blockIdx.y;
  const int b = bh >> 3, h = bh & 7;
  const int l0 = lt * 64;
  const int t = threadIdx.x;
  const int tr = (t >> 4) * 4, tn = (t & 15) * 4;
  load_tile_t(qrT, qs + ((size_t)bh * 512 + l0) * 64, 64);
  if (t < 64) qn_r[t] = qn[bh * 512 + l0 + t];
  const float lsf = log_sf[h];
  float acc[4][4] = {};
  for (int c0 = 0; c0 < 512; c0 += 64) {
    __syncthreads();
    load_tile_t(qcT, qs + ((size_t)bh * 512 + c0) * 64, 64);
    load_tile_n(vgN, vg + ((size_t)bh * 512 + c0) * 64, 64);
    if (t < 64) qn_c[t] = qn[bh * 512 + c0 + t];
    __syncthreads();
    float dt[4][4] = {};
    mma64(qrT, qcT, tr, tn, dt);
    float arow[4], acol[4];
#pragma unroll
    for (int i = 0; i < 4; ++i) arow[i] = -0.5f * qn_r[tr + i];
#pragma unroll
    for (int j = 0; j < 4; ++j) acol[j] = -0.5f * qn_c[tn + j] + lsf;
#pragma unroll
    for (int i = 0; i < 4; ++i)
#pragma unroll
      for (int j = 0; j < 4; ++j)
        sT[(tn + j) * 68 + (tr + i)] = __expf(dt[i][j] + arow[i] + acol[j]);
    __syncthreads();
    mma64(sT, vgN, tr, tn, acc);
  }
  float pb = 0.f;
#pragma unroll
  for (int i = 0; i < 4; ++i) {
    size_t rowbase = ((size_t)bh * 512 + l0 + tr + i) * 64 + tn;
    float4 vgr = *(const float4*)(vg + rowbase);
    float4 mb = *(const float4*)(meanbuf + rowbase);
    pb += acc[i][0] * vgr.x + acc[i][1] * vgr.y + acc[i][2] * vgr.z + acc[i][3] * vgr.w;
    mb.x += acc[i][0]; mb.y += acc[i][1]; mb.z += acc[i][2]; mb.w += acc[i][3];
    *(float4*)(meanbuf + rowbase) = mb;
  }
  redp[t] = pb;
  __syncthreads();
  if (t < 64) {
    float s = redp[t] + redp[t + 64] + redp[t + 128] + redp[t + 192];
#pragma unroll
    for (int off = 32; off > 0; off >>= 1) s += __shfl_down(s, off);
    if (t == 0) atomicAdd(&klbuf[3 + b], (double)s);
  }
}

// ---------- k10_mfma: v3sq[b,h,d,l] = || v1_l^T S_hd ||^2 via MFMA ----------
// R9 redesign: 1-product bf16 (tolerance headroom ~5e3), fragment-level
// exact triangular skip ((kk=0,ns>=2) covers m<32<=n -> S==0), register-
// resident A reused over all 16 d, double-buffered B, full unroll.
// Grid (bh=64, ltq=4, dz=4), block 256 = 4 waves; wave wv owns 2 l-strips
// at ltq*128 + wv*32 (+0, +16).
__global__ __launch_bounds__(256) void k10_mfma(const unsigned short* __restrict__ v1h,
                                                const unsigned short* __restrict__ sth,
                                                float* __restrict__ v3) {
  const int bh = blockIdx.x;
  const int l0 = blockIdx.y * 128;
  const int dz = blockIdx.z;
  const int h = bh & 7;
  const int t = threadIdx.x;
  const int wv = t >> 6;
  const int lane = t & 63;
  const int lr = lane & 15;
  const int kq = lane >> 4;
  const int lbase = l0 + wv * 32;
  // A fragments: 2 strips x 2 kk, reused for all 16 d (16 VGPR)
  bf16x8 a[2][2];
#pragma unroll
  for (int s = 0; s < 2; ++s)
#pragma unroll
    for (int kk = 0; kk < 2; ++kk)
      a[s][kk] = *(const bf16x8*)(v1h + ((size_t)bh * 512 + lbase + s * 16 + lr) * 64 +
                                  kk * 32 + kq * 8);
  const unsigned short* sbase = sth + (size_t)(h * 64 + dz * 16) * 4096;
  // B fragments (6 after tri-skip): [0..3]=(kk=1,ns), [4..5]=(kk=0,ns=0/1)
  bf16x8 b[2][6];
#pragma unroll
  for (int ns = 0; ns < 4; ++ns)
    b[0][ns] = *(const bf16x8*)(sbase + (size_t)(ns * 16 + lr) * 64 + 32 + kq * 8);
#pragma unroll
  for (int ns = 0; ns < 2; ++ns)
    b[0][4 + ns] = *(const bf16x8*)(sbase + (size_t)(ns * 16 + lr) * 64 + kq * 8);
#pragma unroll
  for (int dd = 0; dd < 16; ++dd) {
    const int cur = dd & 1, nxt = cur ^ 1;
    if (dd < 15) {  // prefetch next d's B while computing current
      const unsigned short* sb = sbase + (size_t)(dd + 1) * 4096;
#pragma unroll
      for (int ns = 0; ns < 4; ++ns)
        b[nxt][ns] = *(const bf16x8*)(sb + (size_t)(ns * 16 + lr) * 64 + 32 + kq * 8);
#pragma unroll
      for (int ns = 0; ns < 2; ++ns)
        b[nxt][4 + ns] = *(const bf16x8*)(sb + (size_t)(ns * 16 + lr) * 64 + kq * 8);
    }
#pragma unroll
    for (int s = 0; s < 2; ++s) {
      f32x4 acc[4];
#pragma unroll
      for (int ns = 0; ns < 4; ++ns) acc[ns] = (f32x4){0.f, 0.f, 0.f, 0.f};
#pragma unroll
      for (int ns = 0; ns < 4; ++ns)
        acc[ns] = __builtin_amdgcn_mfma_f32_16x16x32_bf16(a[s][1], b[cur][ns], acc[ns], 0, 0, 0);
#pragma unroll
      for (int ns = 0; ns < 2; ++ns)
        acc[ns] = __builtin_amdgcn_mfma_f32_16x16x32_bf16(a[s][0], b[cur][4 + ns], acc[ns], 0, 0, 0);
      float sum[4];
#pragma unroll
      for (int r = 0; r < 4; ++r)
        sum[r] = acc[0][r] * acc[0][r] + acc[1][r] * acc[1][r] + acc[2][r] * acc[2][r] +
                 acc[3][r] * acc[3][r];
#pragma unroll
      for (int off = 1; off <= 8; off <<= 1)
#pragma unroll
        for (int r = 0; r < 4; ++r) sum[r] += __shfl_xor(sum[r], off);
      if (lr == 0) {
        const int d = dz * 16 + dd;
        const size_t base = ((size_t)(bh * 64 + d)) * 512 + lbase + s * 16 + kq * 4;
        v3[base + 0] = sum[0];
        v3[base + 1] = sum[1];
        v3[base + 2] = sum[2];
        v3[base + 3] = sum[3];
      }
    }
  }
}

// ---------- k8: mean2, chol_covar, samples -> bf16 hi/lo ----------
__global__ __launch_bounds__(256) void k8_samples(
    const float* __restrict__ v1, const float* __restrict__ v2,
    const float* __restrict__ meanbuf, const float* __restrict__ v3,
    const float* __restrict__ v1sq, const float* __restrict__ eps,
    const float* __restrict__ log_sf, unsigned short* __restrict__ smph,
    unsigned short* __restrict__ smpl) {
  extern __shared__ float lds[];
  float* v1T = lds;
  float* v2N = lds + 4352;
  float* v3T = lds + 2 * 4352;
  __shared__ float v1sq_s[64];
  const int lt = blockIdx.x, bh = blockIdx.y;
  const int b = bh >> 3, h = bh & 7;
  const int l0 = lt * 64;
  const int t = threadIdx.x;
  const int tr = (t >> 4) * 4, tn = (t & 15) * 4;
  load_tile_t(v1T, v1 + ((size_t)bh * 512 + l0) * 64, 64);
  load_tile_n(v2N, v2 + (size_t)bh * 4096, 64);
  load_tile_n(v3T, v3 + (size_t)bh * 64 * 512 + l0, 512);
  if (t < 64) v1sq_s[t] = v1sq[bh * 512 + l0 + t];
  __syncthreads();
  float acc[4][4] = {};
  mma64(v1T, v2N, tr, tn, acc);
  const float sf = __expf(log_sf[h]);
#pragma unroll
  for (int i = 0; i < 4; ++i) {
    const int l = l0 + tr + i;
    size_t mbase = ((size_t)bh * 512 + l) * 64 + tn;
    float4 mb = *(const float4*)(meanbuf + mbase);
    float mean[4] = {mb.x - acc[i][0], mb.y - acc[i][1], mb.z - acc[i][2], mb.w - acc[i][3]};
    float cc[4];
#pragma unroll
    for (int j = 0; j < 4; ++j) {
      float var = sf + v3T[(tn + j) * 68 + (tr + i)] - v1sq_s[tr + i];
      cc[j] = sqrtf(fmaxf(var, 0.f));  // true posterior var >= 0; clamp kills NaN
    }
#pragma unroll
    for (int s2 = 0; s2 < 2; ++s2) {
      float4 ep = *(const float4*)(eps + (((size_t)bh * 2 + s2) * 512 + l) * 64 + tn);
      float o[4];
      o[0] = mean[0] + cc[0] * ep.x;
      o[1] = mean[1] + cc[1] * ep.y;
      o[2] = mean[2] + cc[2] * ep.z;
      o[3] = mean[3] + cc[3] * ep.w;
      short4 sh, sl;
      unsigned short hh, ll;
      splitbf(o[0], hh, ll); sh.x = (short)hh; sl.x = (short)ll;
      splitbf(o[1], hh, ll); sh.y = (short)hh; sl.y = (short)ll;
      splitbf(o[2], hh, ll); sh.z = (short)hh; sl.z = (short)ll;
      splitbf(o[3], hh, ll); sh.w = (short)hh; sl.w = (short)ll;
      const size_t obase = (((size_t)(b * 2 + s2) * 512 + l) * 512) + h * 64 + tn;
      *(short4*)(smph + obase) = sh;
      *(short4*)(smpl + obase) = sl;
    }
  }
}

// ---------- gemm1_mfma: out = samples @ W_O^T + bias ----------
__global__ __launch_bounds__(256) void gemm1_mfma(const unsigned short* __restrict__ smph,
                                                  const unsigned short* __restrict__ smpl,
                                                  const unsigned short* __restrict__ woh,
                                                  const unsigned short* __restrict__ wol,
                                                  const float* __restrict__ bias,
                                                  float* __restrict__ out) {
  const int r0 = blockIdx.x * 64;
  const int n0 = blockIdx.y * 64;
  const int t = threadIdx.x;
  const int wv = t >> 6;
  const int lane = t & 63;
  const int lr = lane & 15;
  const int kq = lane >> 4;
  const size_t arow = ((size_t)(r0 + wv * 16 + lr)) * 512;
  f32x4 acc[4];
#pragma unroll
  for (int ns = 0; ns < 4; ++ns) acc[ns] = (f32x4){0.f, 0.f, 0.f, 0.f};
  for (int ks = 0; ks < 16; ++ks) {
    const int kb = ks * 32 + kq * 8;
    bf16x8 ah = *(const bf16x8*)(smph + arow + kb);
    bf16x8 al = *(const bf16x8*)(smpl + arow + kb);
#pragma unroll
    for (int ns = 0; ns < 4; ++ns) {
      const size_t brow = ((size_t)(n0 + ns * 16 + lr)) * 512 + kb;
      bf16x8 bh8 = *(const bf16x8*)(woh + brow);
      bf16x8 bl8 = *(const bf16x8*)(wol + brow);
      acc[ns] = __builtin_amdgcn_mfma_f32_16x16x32_bf16(ah, bh8, acc[ns], 0, 0, 0);
      acc[ns] = __builtin_amdgcn_mfma_f32_16x16x32_bf16(ah, bl8, acc[ns], 0, 0, 0);
      acc[ns] = __builtin_amdgcn_mfma_f32_16x16x32_bf16(al, bh8, acc[ns], 0, 0, 0);
    }
  }
#pragma unroll
  for (int ns = 0; ns < 4; ++ns) {
    const int outc = n0 + ns * 16 + lr;
    const float bc = bias[outc];
    const int rbase = r0 + wv * 16 + kq * 4;
#pragma unroll
    for (int r = 0; r < 4; ++r) {
      out[(size_t)(rbase + r) * 512 + outc] = acc[ns][r] + bc;
    }
  }
}

// ---------- kfin ----------
__global__ void kfin(const double* __restrict__ klbuf, float* __restrict__ dout) {
  if (threadIdx.x == 0 && blockIdx.x == 0) {
    double pb = 0.0;
    for (int b = 0; b < 8; ++b) pb += klbuf[3 + b] - klbuf[11 + b];
    double kl = -16384.0 + klbuf[0] + klbuf[1] - klbuf[2] + pb / 16.0;
    dout[4194304] = (float)kl;
  }
}

extern "C" void kernel_launch(void* const* d_in, const int* in_sizes, int n_in,
                              void* d_out, int out_size, void* d_ws, size_t ws_size,
                              hipStream_t stream) {
  (void)in_sizes; (void)n_in; (void)out_size; (void)ws_size;
  const float* x     = (const float*)d_in[0];
  const float* cur_k = (const float*)d_in[1];
  const float* eps   = (const float*)d_in[2];
  const float* W_qkv = (const float*)d_in[3];
  const float* lsf   = (const float*)d_in[4];
  const float* lls   = (const float*)d_in[5];
  const float* vind  = (const float*)d_in[6];
  const float* ltri  = (const float*)d_in[7];
  const float* ldia  = (const float*)d_in[8];
  const float* Wo    = (const float*)d_in[9];
  const float* Wob   = (const float*)d_in[10];
  float* out = (float*)d_out;
  float* ws = (float*)d_ws;
  float* qs   = ws + OFF_QS;
  float* vg   = ws + OFF_VG;
  float* qn   = ws + OFF_QN;
  float* kbs  = ws + OFF_KBS;
  float* kbn  = ws + OFF_KBN;
  float* linv = ws + OFF_LINV;
  float* v1   = ws + OFF_V1;
  float* v1s  = ws + OFF_V1SQ;
  float* mean = ws + OFF_MEAN;
  float* v2   = ws + OFF_V2;
  float* v3   = ws + OFF_V3;
  unsigned short* v1h = (unsigned short*)(ws + OFF_V1H);
  unsigned short* v1l = (unsigned short*)(ws + OFF_V1L);
  unsigned short* sth = (unsigned short*)(ws + OFF_STH);
  unsigned short* stl = (unsigned short*)(ws + OFF_STL);
  unsigned short* woh = (unsigned short*)(ws + OFF_WOH);
  unsigned short* wol = (unsigned short*)(ws + OFF_WOL);
  unsigned short* smph = (unsigned short*)(ws + OFF_QS);  // reuse qs (dead after k6)
  unsigned short* smpl = (unsigned short*)(ws + OFF_VG);  // reuse vg (dead after k6)
  double* kld = (double*)(ws + OFF_KLD);

  hipMemsetAsync(kld, 0, 32 * sizeof(double), stream);
  gemm0<<<dim3(64, 16), 256, 0, stream>>>(x, W_qkv, qs, vg, lls, qn);
  k2_kbeta<<<512, 256, 0, stream>>>(W_qkv, cur_k, lls, kbs, kbn);
  k3_chol<<<8, 64, 0, stream>>>(kbs, kbn, vind, lsf, linv, kld);
  ks_build<<<512, 256, 0, stream>>>(ltri, ldia, sth, stl, kld);
  kconv_wo<<<1024, 256, 0, stream>>>(Wo, woh, wol);
  k4_fused<<<dim3(8, 64), 256, 73984, stream>>>(qs, qn, kbs, kbn, linv, vind, lsf,
                                                v1, v1h, v1l, v1s, mean);
  k5_v2<<<64, 256, 0, stream>>>(v1, vg, v2, kld);
  k6_mean1<<<dim3(8, 64), 256, 69632, stream>>>(qs, qn, vg, lsf, mean, kld);
  k10_mfma<<<dim3(64, 4, 4), 256, 0, stream>>>(v1h, sth, v3);
  k8_samples<<<dim3(8, 64), 256, 52224, stream>>>(v1, v2, mean, v3, v1s, eps, lsf,
                                                  smph, smpl);
  gemm1_mfma<<<dim3(128, 8), 256, 0, stream>>>(smph, smpl, woh, wol, Wob, out);
  kfin<<<1, 64, 0, stream>>>(kld, out);
}

// Round 11
// 567.733 us; speedup vs baseline: 1.3919x; 1.0779x over previous
//
#include <hip/hip_runtime.h>
#include <math.h>

// B=8, L=512, H=8, vd=64, M=64, S=2, hdim=512. f32 in/out.
// R11: k3 split into k3a (parallel K_kk build + vKv, 256 thr) and k3b
// (register-resident fused Cholesky+Linv, static-unrolled, 64 thr) —
// replaces the 165us latency-bound serial k3_chol. Dead stl/v1l writes
// removed (k10 uses hi-parts only since R9).

using bf16x8 = __attribute__((ext_vector_type(8))) short;
using f32x4  = __attribute__((ext_vector_type(4))) float;

// ---- workspace layout (float units) ----
static const size_t OFF_QS   = 0;                       // 2097152 (k8: smph)
static const size_t OFF_VG   = OFF_QS   + 2097152;      // 2097152 (k8: smpl)
static const size_t OFF_QN   = OFF_VG   + 2097152;      // 32768
static const size_t OFF_KBS  = OFF_QN   + 32768;        // 32768
static const size_t OFF_KBN  = OFF_KBS  + 32768;        // 512
static const size_t OFF_LINV = OFF_KBN  + 512;          // 32768
static const size_t OFF_V1   = OFF_LINV + 32768;        // 2097152
static const size_t OFF_V1SQ = OFF_V1   + 2097152;      // 32768
static const size_t OFF_MEAN = OFF_V1SQ + 32768;        // 2097152
static const size_t OFF_V2   = OFF_MEAN + 2097152;      // 262144
static const size_t OFF_V1H  = OFF_V2   + 262144;       // 1048576 (2097152 shorts)
static const size_t OFF_V1L  = OFF_V1H  + 1048576;      // 1048576 (unused now)
static const size_t OFF_STH  = OFF_V1L  + 1048576;      // 1048576 (2097152 shorts)
static const size_t OFF_KKK  = OFF_STH  + 1048576;      // 32768 (K_kk+jitter, 8x64x64)
static const size_t OFF_PAD0 = OFF_KKK  + 32768;        // 1015808 (spare)
static const size_t OFF_V3   = OFF_PAD0 + 1015808;      // 2097152
static const size_t OFF_WOH  = OFF_V3   + 2097152;      // 131072
static const size_t OFF_WOL  = OFF_WOH  + 131072;       // 131072
static const size_t OFF_KLD  = OFF_WOL  + 131072;       // 64 (32 doubles)

// ---------- bf16 split helpers ----------
__device__ __forceinline__ unsigned short f2bf(float x) {
  unsigned u = __float_as_uint(x);
  u += 0x7FFFu + ((u >> 16) & 1u);
  return (unsigned short)(u >> 16);
}
__device__ __forceinline__ float bf2f(unsigned short s) {
  return __uint_as_float(((unsigned)s) << 16);
}
__device__ __forceinline__ void splitbf(float x, unsigned short& h, unsigned short& l) {
  h = f2bf(x);
  l = f2bf(x - bf2f(h));
}

// ---------- LDS tile helpers (blockDim.x == 256) ----------
__device__ __forceinline__ void load_tile_t(float* dst, const float* src, int ld) {
  int t = threadIdx.x;
  int r = t >> 2;
  int c0 = (t & 3) * 16;
#pragma unroll
  for (int q = 0; q < 4; ++q) {
    float4 v = *(const float4*)(src + (size_t)r * ld + c0 + q * 4);
    int c = c0 + q * 4;
    dst[(c + 0) * 68 + r] = v.x;
    dst[(c + 1) * 68 + r] = v.y;
    dst[(c + 2) * 68 + r] = v.z;
    dst[(c + 3) * 68 + r] = v.w;
  }
}
__device__ __forceinline__ void load_tile_n(float* dst, const float* src, int ld) {
  int t = threadIdx.x;
  int r = t >> 2;
  int c0 = (t & 3) * 16;
#pragma unroll
  for (int q = 0; q < 4; ++q) {
    float4 v = *(const float4*)(src + (size_t)r * ld + c0 + q * 4);
    *(float4*)(dst + r * 68 + c0 + q * 4) = v;
  }
}
__device__ __forceinline__ void mma64(const float* aT, const float* bT, int tr, int tn,
                                      float acc[4][4]) {
#pragma unroll 16
  for (int k = 0; k < 64; ++k) {
    float4 av = *(const float4*)(aT + k * 68 + tr);
    float4 bv = *(const float4*)(bT + k * 68 + tn);
    float a[4] = {av.x, av.y, av.z, av.w};
    float b[4] = {bv.x, bv.y, bv.z, bv.w};
#pragma unroll
    for (int i = 0; i < 4; ++i)
#pragma unroll
      for (int j = 0; j < 4; ++j) acc[i][j] = fmaf(a[i], b[j], acc[i][j]);
  }
}
__device__ __forceinline__ void mma64_dual(const float* aT, const float* b1T,
                                           const float* b2T, int tr, int tn,
                                           float acc1[4][4], float acc2[4][4]) {
#pragma unroll 8
  for (int k = 0; k < 64; ++k) {
    float4 av = *(const float4*)(aT + k * 68 + tr);
    float4 b1 = *(const float4*)(b1T + k * 68 + tn);
    float4 b2 = *(const float4*)(b2T + k * 68 + tn);
    float a[4] = {av.x, av.y, av.z, av.w};
    float p[4] = {b1.x, b1.y, b1.z, b1.w};
    float q[4] = {b2.x, b2.y, b2.z, b2.w};
#pragma unroll
    for (int i = 0; i < 4; ++i)
#pragma unroll
      for (int j = 0; j < 4; ++j) {
        acc1[i][j] = fmaf(a[i], p[j], acc1[i][j]);
        acc2[i][j] = fmaf(a[i], q[j], acc2[i][j]);
      }
  }
}

// ---------- gemm0: qkv GEMM + scatter + fused qn ----------
__global__ __launch_bounds__(256) void gemm0(
    const float* __restrict__ A, const float* __restrict__ Bm,
    float* __restrict__ qs, float* __restrict__ vg, const float* __restrict__ lls,
    float* __restrict__ qn) {
  __shared__ float As[16][68];
  __shared__ float Bs[16][68];
  const int t = threadIdx.x;
  const int r0 = blockIdx.x * 64;
  const int n0 = blockIdx.y * 64;
  const int lr = t >> 2;
  const int lk = (t & 3) * 4;
  const int tr = (t >> 4) * 4;
  const int tn = (t & 15) * 4;
  const float* Ap = A + (size_t)(r0 + lr) * 512 + lk;
  const float* Bp = Bm + (size_t)(n0 + lr) * 512 + lk;
  float acc[4][4] = {};
  for (int k0 = 0; k0 < 512; k0 += 16) {
    float4 a4 = *(const float4*)(Ap + k0);
    float4 b4 = *(const float4*)(Bp + k0);
    As[lk + 0][lr] = a4.x; As[lk + 1][lr] = a4.y; As[lk + 2][lr] = a4.z; As[lk + 3][lr] = a4.w;
    Bs[lk + 0][lr] = b4.x; Bs[lk + 1][lr] = b4.y; Bs[lk + 2][lr] = b4.z; Bs[lk + 3][lr] = b4.w;
    __syncthreads();
#pragma unroll
    for (int k = 0; k < 16; ++k) {
      float4 av = *(const float4*)&As[k][tr];
      float4 bv = *(const float4*)&Bs[k][tn];
      float a[4] = {av.x, av.y, av.z, av.w};
      float b[4] = {bv.x, bv.y, bv.z, bv.w};
#pragma unroll
      for (int i = 0; i < 4; ++i)
#pragma unroll
        for (int j = 0; j < 4; ++j) acc[i][j] = fmaf(a[i], b[j], acc[i][j]);
    }
    __syncthreads();
  }
  const int h = n0 >> 7;
  const bool isq = (n0 & 64) == 0;
  if (isq) {
    float invls[4];
#pragma unroll
    for (int j = 0; j < 4; ++j) invls[j] = __expf(-lls[h * 64 + tn + j]);
    float* red = &As[0][0];  // 16*68 = 1088 = 64*17
#pragma unroll
    for (int i = 0; i < 4; ++i) {
      int r = r0 + tr + i;
      int b = r >> 9, l = r & 511;
      float4 o;
      o.x = acc[i][0] * invls[0];
      o.y = acc[i][1] * invls[1];
      o.z = acc[i][2] * invls[2];
      o.w = acc[i][3] * invls[3];
      *(float4*)(qs + (((size_t)(b * 8 + h)) * 512 + l) * 64 + tn) = o;
      red[(tr + i) * 17 + (t & 15)] = o.x * o.x + o.y * o.y + o.z * o.z + o.w * o.w;
    }
    __syncthreads();
    if (t < 64) {
      float s = 0.f;
#pragma unroll
      for (int g = 0; g < 16; ++g) s += red[t * 17 + g];
      int r = r0 + t;
      int b = r >> 9, l = r & 511;
      qn[(b * 8 + h) * 512 + l] = s;
    }
  } else {
#pragma unroll
    for (int i = 0; i < 4; ++i) {
      int r = r0 + tr + i;
      int b = r >> 9, l = r & 511;
      float4 o = {acc[i][0], acc[i][1], acc[i][2], acc[i][3]};
      *(float4*)(vg + (((size_t)(b * 8 + h)) * 512 + l) * 64 + tn) = o;
    }
  }
}

// ---------- k2: k_beta + norms ----------
__global__ __launch_bounds__(256) void k2_kbeta(const float* __restrict__ W,
                                                const float* __restrict__ ckg,
                                                const float* __restrict__ log_ls,
                                                float* __restrict__ kbs,
                                                float* __restrict__ kbn) {
  __shared__ float ck[512];
  __shared__ float kb[64];
  int h = blockIdx.x >> 6, m = blockIdx.x & 63;
  int t = threadIdx.x;
  ck[t] = ckg[m * 512 + t];
  ck[t + 256] = ckg[m * 512 + t + 256];
  __syncthreads();
  int w = t >> 6, lane = t & 63;
  for (int d = w; d < 64; d += 4) {
    const float* row = W + (size_t)(h * 64 + d) * 512;
    float p = 0.f;
    for (int k = lane; k < 512; k += 64) p = fmaf(row[k], ck[k], p);
#pragma unroll
    for (int off = 32; off > 0; off >>= 1) p += __shfl_down(p, off);
    if (lane == 0) {
      float v = p * __expf(-log_ls[h * 64 + d]);
      kbs[(size_t)h * 4096 + m * 64 + d] = v;
      kb[d] = v;
    }
  }
  __syncthreads();
  if (w == 0) {
    float v = kb[lane];
    v *= v;
#pragma unroll
    for (int off = 32; off > 0; off >>= 1) v += __shfl_down(v, off);
    if (lane == 0) kbn[h * 64 + m] = v;
  }
}

// ---------- k3a: K_kk build + KL vKv (parallel, 256 thr/block) ----------
__global__ __launch_bounds__(256) void k3a_build(const float* __restrict__ kbs,
                                                 const float* __restrict__ kbn,
                                                 const float* __restrict__ vind,
                                                 const float* __restrict__ log_sf,
                                                 float* __restrict__ kkk,
                                                 double* __restrict__ klbuf) {
  __shared__ float Bm[64 * 68];
  __shared__ float Vb[64 * 68];
  __shared__ float Am[64 * 68];
  __shared__ float kn[64];
  __shared__ float redp[256];
  const int h = blockIdx.x;
  const int t = threadIdx.x;
  load_tile_n(Bm, kbs + (size_t)h * 4096, 64);
  load_tile_n(Vb, vind + (size_t)h * 4096, 64);
  if (t < 64) kn[t] = kbn[h * 64 + t];
  const float lsf = log_sf[h];
  __syncthreads();
  // K build: thread (m = t>>2, q = t&3) covers n = q + 4*nn (bank-spread)
  {
    const int m = t >> 2, q = t & 3;
    float rowm[64];
#pragma unroll
    for (int d = 0; d < 64; ++d) rowm[d] = Bm[m * 68 + d];
    const float cm = -0.5f * kn[m] + lsf;
#pragma unroll
    for (int nn = 0; nn < 16; ++nn) {
      const int n = q + nn * 4;
      float dt = 0.f;
#pragma unroll
      for (int d = 0; d < 64; ++d) dt = fmaf(rowm[d], Bm[n * 68 + d], dt);
      Am[m * 68 + n] = __expf(dt + cm - 0.5f * kn[n]);
    }
  }
  __syncthreads();
  // vKv (pre-jitter): thread (d = t&63, wave q2 = t>>6) covers 16 m rows
  {
    const int d = t & 63, q2 = t >> 6;
    float sp = 0.f;
#pragma unroll
    for (int mm = 0; mm < 16; ++mm) {
      const int m = q2 * 16 + mm;
      float tt = 0.f;
#pragma unroll
      for (int n = 0; n < 64; ++n) tt = fmaf(Am[m * 68 + n], Vb[n * 68 + d], tt);
      sp = fmaf(Vb[m * 68 + d], tt, sp);
    }
    redp[t] = sp;
  }
  __syncthreads();
  for (int sft = 128; sft > 0; sft >>= 1) {
    if (t < sft) redp[t] += redp[t + sft];
    __syncthreads();
  }
  if (t == 0) atomicAdd(&klbuf[1], 0.5 * (double)redp[0]);
  // store K_kk + jitter
#pragma unroll
  for (int rep = 0; rep < 16; ++rep) {
    const int i = rep * 256 + t;
    const int m = i >> 6, n = i & 63;
    kkk[(size_t)h * 4096 + i] = Am[m * 68 + n] + (m == n ? 1e-4f : 0.f);
  }
}

// ---------- k3b: fused register Cholesky + Linv (64 thr = 1 wave) ------
// Thread t owns column t of A (a[64] regs) and column t of X=L^-1 (x[64]).
// Fully-static unrolled k-loop: per step, thread k publishes scaled column
// k via LDS broadcast; all threads apply rank-1 updates (2 FMA / bcast read).
__global__ __launch_bounds__(64) void k3b_cholinv(const float* __restrict__ kkk,
                                                  float* __restrict__ linv_g) {
  __shared__ float colk[64];
  __shared__ float rinv_s;
  const int h = blockIdx.x;
  const int t = threadIdx.x;
  float a[64], x[64];
#pragma unroll
  for (int i = 0; i < 64; ++i) a[i] = kkk[(size_t)h * 4096 + i * 64 + t];
#pragma unroll
  for (int i = 0; i < 64; ++i) x[i] = (i == t) ? 1.f : 0.f;
#pragma unroll
  for (int k = 0; k < 64; ++k) {
    if (t == k) {
      const float dk = sqrtf(a[k]);
      const float ri = 1.f / dk;
      rinv_s = ri;
#pragma unroll
      for (int i = k + 1; i < 64; ++i) {
        a[i] *= ri;
        colk[i] = a[i];
      }
    }
    __syncthreads();
    const float ri = rinv_s;
    const float fc = (t > k) ? colk[t] : 0.f;
    const float xk = x[k] * ri;
    x[k] = xk;
#pragma unroll
    for (int i = k + 1; i < 64; ++i) {
      const float ci = colk[i];
      a[i] = fmaf(-fc, ci, a[i]);
      x[i] = fmaf(-ci, xk, x[i]);
    }
    __syncthreads();
  }
#pragma unroll
  for (int m = 0; m < 64; ++m) linv_g[(size_t)h * 4096 + m * 64 + t] = x[m];
}

// ---------- ks_build: S^T bf16 hi + KL terms ----------
__global__ __launch_bounds__(256) void ks_build(const float* __restrict__ ltri,
                                                const float* __restrict__ ldiag,
                                                unsigned short* __restrict__ sth,
                                                double* __restrict__ klbuf) {
  __shared__ float r1[256], r2[256];
  int hd = blockIdx.x;
  int t = threadIdx.x;
  float p2 = 0.f, pl = 0.f;
  for (int i = t; i < 4096; i += 256) {
    int n = i >> 6, m = i & 63;  // output-major (transposed)
    float v;
    if (m == n) v = __expf(ldiag[hd * 64 + m]);
    else if (m > n) v = ltri[(size_t)hd * 4096 + m * 64 + n];
    else v = 0.f;
    sth[(size_t)hd * 4096 + i] = f2bf(v);
    p2 = fmaf(0.5f * v, v, p2);
  }
  if (t < 64) pl = ldiag[hd * 64 + t];
  r1[t] = p2;
  r2[t] = pl;
  __syncthreads();
  for (int sft = 128; sft > 0; sft >>= 1) {
    if (t < sft) { r1[t] += r1[t + sft]; r2[t] += r2[t + sft]; }
    __syncthreads();
  }
  if (t == 0) {
    atomicAdd(&klbuf[0], (double)r1[0]);
    atomicAdd(&klbuf[2], (double)r2[0]);
  }
}

// ---------- kconv_wo: split W_O to bf16 hi/lo ----------
__global__ __launch_bounds__(256) void kconv_wo(const float* __restrict__ w,
                                                unsigned short* __restrict__ wh,
                                                unsigned short* __restrict__ wl) {
  int i = blockIdx.x * 256 + threadIdx.x;  // 262144 total
  float v = w[i];
  unsigned short h, l;
  splitbf(v, h, l);
  wh[i] = h;
  wl[i] = l;
}

// ---------- k4: K_qk -> v1 (f32 + bf16 hi), v1sq, meanA ----------
__global__ __launch_bounds__(256) void k4_fused(
    const float* __restrict__ qs, const float* __restrict__ qn,
    const float* __restrict__ kbs, const float* __restrict__ kbn,
    const float* __restrict__ linv, const float* __restrict__ vind,
    const float* __restrict__ log_sf, float* __restrict__ v1,
    unsigned short* __restrict__ v1h,
    float* __restrict__ v1sq, float* __restrict__ meanbuf) {
  extern __shared__ float lds[];
  float* qsT = lds;
  float* kbT = lds + 4352;
  float* liT = lds + 2 * 4352;
  float* vbN = lds + 3 * 4352;
  float* red = lds + 4 * 4352;
  __shared__ float qn_s[64], kbn_s[64];
  const int lt = blockIdx.x, bh = blockIdx.y;
  const int h = bh & 7;
  const int t = threadIdx.x;
  const int l0 = lt * 64;
  const int tr = (t >> 4) * 4, tn = (t & 15) * 4;
  load_tile_t(qsT, qs + ((size_t)bh * 512 + l0) * 64, 64);
  load_tile_t(kbT, kbs + (size_t)h * 4096, 64);
  load_tile_t(liT, linv + (size_t)h * 4096, 64);
  load_tile_n(vbN, vind + (size_t)h * 4096, 64);
  if (t < 64) {
    qn_s[t] = qn[bh * 512 + l0 + t];
    kbn_s[t] = kbn[h * 64 + t];
  }
  __syncthreads();
  float acc[4][4] = {};
  mma64(qsT, kbT, tr, tn, acc);
  const float lsf = log_sf[h];
  float arow[4], acol[4];
#pragma unroll
  for (int i = 0; i < 4; ++i) arow[i] = -0.5f * qn_s[tr + i];
#pragma unroll
  for (int j = 0; j < 4; ++j) acol[j] = -0.5f * kbn_s[tn + j] + lsf;
  float kv[4][4];
#pragma unroll
  for (int i = 0; i < 4; ++i)
#pragma unroll
    for (int j = 0; j < 4; ++j) kv[i][j] = __expf(acc[i][j] + arow[i] + acol[j]);
  __syncthreads();
#pragma unroll
  for (int i = 0; i < 4; ++i)
#pragma unroll
    for (int j = 0; j < 4; ++j) qsT[(tn + j) * 68 + (tr + i)] = kv[i][j];
  __syncthreads();
  float a2[4][4] = {};
  float a3[4][4] = {};
  mma64_dual(qsT, liT, vbN, tr, tn, a2, a3);
#pragma unroll
  for (int i = 0; i < 4; ++i) {
    const size_t rowbase = ((size_t)bh * 512 + l0 + tr + i) * 64 + tn;
    float4 o = {a2[i][0], a2[i][1], a2[i][2], a2[i][3]};
    *(float4*)(v1 + rowbase) = o;
    short4 sh;
    sh.x = (short)f2bf(o.x);
    sh.y = (short)f2bf(o.y);
    sh.z = (short)f2bf(o.z);
    sh.w = (short)f2bf(o.w);
    *(short4*)(v1h + rowbase) = sh;
    red[(tr + i) * 17 + (t & 15)] =
        a2[i][0] * a2[i][0] + a2[i][1] * a2[i][1] + a2[i][2] * a2[i][2] + a2[i][3] * a2[i][3];
    float4 o3 = {a3[i][0], a3[i][1], a3[i][2], a3[i][3]};
    *(float4*)(meanbuf + rowbase) = o3;
  }
  __syncthreads();
  if (t < 64) {
    float s2 = 0.f;
#pragma unroll
    for (int g = 0; g < 16; ++g) s2 += red[t * 17 + g];
    v1sq[bh * 512 + l0 + t] = s2;
  }
}

// ---------- k5: v2 = v1^T @ v_gamma; + KL v2^2 ----------
__global__ __launch_bounds__(256) void k5_v2(const float* __restrict__ v1,
                                             const float* __restrict__ vg,
                                             float* __restrict__ v2,
                                             double* __restrict__ klbuf) {
  __shared__ float v1t[64 * 68];
  __shared__ float vgt[64 * 68];
  __shared__ float redp[256];
  const int bh = blockIdx.x;
  const int b = bh >> 3;
  const int t = threadIdx.x;
  const int tr = (t >> 4) * 4, tn = (t & 15) * 4;
  float acc[4][4] = {};
  for (int c0 = 0; c0 < 512; c0 += 64) {
    __syncthreads();
    load_tile_n(v1t, v1 + ((size_t)bh * 512 + c0) * 64, 64);
    load_tile_n(vgt, vg + ((size_t)bh * 512 + c0) * 64, 64);
    __syncthreads();
    mma64(v1t, vgt, tr, tn, acc);
  }
  float p = 0.f;
#pragma unroll
  for (int i = 0; i < 4; ++i) {
    float4 o = {acc[i][0], acc[i][1], acc[i][2], acc[i][3]};
    *(float4*)(v2 + ((size_t)bh * 64 + tr + i) * 64 + tn) = o;
    p += acc[i][0] * acc[i][0] + acc[i][1] * acc[i][1] + acc[i][2] * acc[i][2] +
         acc[i][3] * acc[i][3];
  }
  redp[t] = p;
  __syncthreads();
  if (t < 64) {
    float s = redp[t] + redp[t + 64] + redp[t + 128] + redp[t + 192];
#pragma unroll
    for (int off = 32; off > 0; off >>= 1) s += __shfl_down(s, off);
    if (t == 0) atomicAdd(&klbuf[11 + b], (double)s);
  }
}

// ---------- k6: mean += K_qq @ v_gamma; KL vg*mean1 ----------
__global__ __launch_bounds__(256) void k6_mean1(const float* __restrict__ qs,
                                                const float* __restrict__ qn,
                                                const float* __restrict__ vg,
                                                const float* __restrict__ log_sf,
                                                float* __restrict__ meanbuf,
                                                double* __restrict__ klbuf) {
  extern __shared__ float lds[];
  float* qrT = lds;
  float* qcT = lds + 4352;
  float* sT = lds + 2 * 4352;
  float* vgN = lds + 3 * 4352;
  __shared__ float qn_r[64], qn_c[64], redp[256];
  const int lt = blockIdx.x, bh = blockIdx.y;
  const int b = bh >> 3, h = bh & 7;
  const int l0 = lt * 64;
  const int t = threadIdx.x;
  const int tr = (t >> 4) * 4, tn = (t & 15) * 4;
  load_tile_t(qrT, qs + ((size_t)bh * 512 + l0) * 64, 64);
  if (t < 64) qn_r[t] = qn[bh * 512 + l0 + t];
  const float lsf = log_sf[h];
  float acc[4][4] = {};
  for (int c0 = 0; c0 < 512; c0 += 64) {
    __syncthreads();
    load_tile_t(qcT, qs + ((size_t)bh * 512 + c0) * 64, 64);
    load_tile_n(vgN, vg + ((size_t)bh * 512 + c0) * 64, 64);
    if (t < 64) qn_c[t] = qn[bh * 512 + c0 + t];
    __syncthreads();
    float dt[4][4] = {};
    mma64(qrT, qcT, tr, tn, dt);
    float arow[4], acol[4];
#pragma unroll
    for (int i = 0; i < 4; ++i) arow[i] = -0.5f * qn_r[tr + i];
#pragma unroll
    for (int j = 0; j < 4; ++j) acol[j] = -0.5f * qn_c[tn + j] + lsf;
#pragma unroll
    for (int i = 0; i < 4; ++i)
#pragma unroll
      for (int j = 0; j < 4; ++j)
        sT[(tn + j) * 68 + (tr + i)] = __expf(dt[i][j] + arow[i] + acol[j]);
    __syncthreads();
    mma64(sT, vgN, tr, tn, acc);
  }
  float pb = 0.f;
#pragma unroll
  for (int i = 0; i < 4; ++i) {
    size_t rowbase = ((size_t)bh * 512 + l0 + tr + i) * 64 + tn;
    float4 vgr = *(const float4*)(vg + rowbase);
    float4 mb = *(const float4*)(meanbuf + rowbase);
    pb += acc[i][0] * vgr.x + acc[i][1] * vgr.y + acc[i][2] * vgr.z + acc[i][3] * vgr.w;
    mb.x += acc[i][0]; mb.y += acc[i][1]; mb.z += acc[i][2]; mb.w += acc[i][3];
    *(float4*)(meanbuf + rowbase) = mb;
  }
  redp[t] = pb;
  __syncthreads();
  if (t < 64) {
    float s = redp[t] + redp[t + 64] + redp[t + 128] + redp[t + 192];
#pragma unroll
    for (int off = 32; off > 0; off >>= 1) s += __shfl_down(s, off);
    if (t == 0) atomicAdd(&klbuf[3 + b], (double)s);
  }
}

// ---------- k10_mfma: v3sq[b,h,d,l] = || v1_l^T S_hd ||^2 via MFMA ----------
__global__ __launch_bounds__(256) void k10_mfma(const unsigned short* __restrict__ v1h,
                                                const unsigned short* __restrict__ sth,
                                                float* __restrict__ v3) {
  const int bh = blockIdx.x;
  const int l0 = blockIdx.y * 128;
  const int dz = blockIdx.z;
  const int h = bh & 7;
  const int t = threadIdx.x;
  const int wv = t >> 6;
  const int lane = t & 63;
  const int lr = lane & 15;
  const int kq = lane >> 4;
  const int lbase = l0 + wv * 32;
  // A fragments: 2 strips x 2 kk, reused for all 16 d (16 VGPR)
  bf16x8 a[2][2];
#pragma unroll
  for (int s = 0; s < 2; ++s)
#pragma unroll
    for (int kk = 0; kk < 2; ++kk)
      a[s][kk] = *(const bf16x8*)(v1h + ((size_t)bh * 512 + lbase + s * 16 + lr) * 64 +
                                  kk * 32 + kq * 8);
  const unsigned short* sbase = sth + (size_t)(h * 64 + dz * 16) * 4096;
  // B fragments (6 after tri-skip): [0..3]=(kk=1,ns), [4..5]=(kk=0,ns=0/1)
  bf16x8 b[2][6];
#pragma unroll
  for (int ns = 0; ns < 4; ++ns)
    b[0][ns] = *(const bf16x8*)(sbase + (size_t)(ns * 16 + lr) * 64 + 32 + kq * 8);
#pragma unroll
  for (int ns = 0; ns < 2; ++ns)
    b[0][4 + ns] = *(const bf16x8*)(sbase + (size_t)(ns * 16 + lr) * 64 + kq * 8);
#pragma unroll
  for (int dd = 0; dd < 16; ++dd) {
    const int cur = dd & 1, nxt = cur ^ 1;
    if (dd < 15) {  // prefetch next d's B while computing current
      const unsigned short* sb = sbase + (size_t)(dd + 1) * 4096;
#pragma unroll
      for (int ns = 0; ns < 4; ++ns)
        b[nxt][ns] = *(const bf16x8*)(sb + (size_t)(ns * 16 + lr) * 64 + 32 + kq * 8);
#pragma unroll
      for (int ns = 0; ns < 2; ++ns)
        b[nxt][4 + ns] = *(const bf16x8*)(sb + (size_t)(ns * 16 + lr) * 64 + kq * 8);
    }
#pragma unroll
    for (int s = 0; s < 2; ++s) {
      f32x4 acc[4];
#pragma unroll
      for (int ns = 0; ns < 4; ++ns) acc[ns] = (f32x4){0.f, 0.f, 0.f, 0.f};
#pragma unroll
      for (int ns = 0; ns < 4; ++ns)
        acc[ns] = __builtin_amdgcn_mfma_f32_16x16x32_bf16(a[s][1], b[cur][ns], acc[ns], 0, 0, 0);
#pragma unroll
      for (int ns = 0; ns < 2; ++ns)
        acc[ns] = __builtin_amdgcn_mfma_f32_16x16x32_bf16(a[s][0], b[cur][4 + ns], acc[ns], 0, 0, 0);
      float sum[4];
#pragma unroll
      for (int r = 0; r < 4; ++r)
        sum[r] = acc[0][r] * acc[0][r] + acc[1][r] * acc[1][r] + acc[2][r] * acc[2][r] +
                 acc[3][r] * acc[3][r];
#pragma unroll
      for (int off = 1; off <= 8; off <<= 1)
#pragma unroll
        for (int r = 0; r < 4; ++r) sum[r] += __shfl_xor(sum[r], off);
      if (lr == 0) {
        const int d = dz * 16 + dd;
        const size_t base = ((size_t)(bh * 64 + d)) * 512 + lbase + s * 16 + kq * 4;
        v3[base + 0] = sum[0];
        v3[base + 1] = sum[1];
        v3[base + 2] = sum[2];
        v3[base + 3] = sum[3];
      }
    }
  }
}

// ---------- k8: mean2, chol_covar, samples -> bf16 hi/lo ----------
__global__ __launch_bounds__(256) void k8_samples(
    const float* __restrict__ v1, const float* __restrict__ v2,
    const float* __restrict__ meanbuf, const float* __restrict__ v3,
    const float* __restrict__ v1sq, const float* __restrict__ eps,
    const float* __restrict__ log_sf, unsigned short* __restrict__ smph,
    unsigned short* __restrict__ smpl) {
  extern __shared__ float lds[];
  float* v1T = lds;
  float* v2N = lds + 4352;
  float* v3T = lds + 2 * 4352;
  __shared__ float v1sq_s[64];
  const int lt = blockIdx.x, bh = blockIdx.y;
  const int b = bh >> 3, h = bh & 7;
  const int l0 = lt * 64;
  const int t = threadIdx.x;
  const int tr = (t >> 4) * 4, tn = (t & 15) * 4;
  load_tile_t(v1T, v1 + ((size_t)bh * 512 + l0) * 64, 64);
  load_tile_n(v2N, v2 + (size_t)bh * 4096, 64);
  load_tile_n(v3T, v3 + (size_t)bh * 64 * 512 + l0, 512);
  if (t < 64) v1sq_s[t] = v1sq[bh * 512 + l0 + t];
  __syncthreads();
  float acc[4][4] = {};
  mma64(v1T, v2N, tr, tn, acc);
  const float sf = __expf(log_sf[h]);
#pragma unroll
  for (int i = 0; i < 4; ++i) {
    const int l = l0 + tr + i;
    size_t mbase = ((size_t)bh * 512 + l) * 64 + tn;
    float4 mb = *(const float4*)(meanbuf + mbase);
    float mean[4] = {mb.x - acc[i][0], mb.y - acc[i][1], mb.z - acc[i][2], mb.w - acc[i][3]};
    float cc[4];
#pragma unroll
    for (int j = 0; j < 4; ++j) {
      float var = sf + v3T[(tn + j) * 68 + (tr + i)] - v1sq_s[tr + i];
      cc[j] = sqrtf(fmaxf(var, 0.f));  // true posterior var >= 0; clamp kills NaN
    }
#pragma unroll
    for (int s2 = 0; s2 < 2; ++s2) {
      float4 ep = *(const float4*)(eps + (((size_t)bh * 2 + s2) * 512 + l) * 64 + tn);
      float o[4];
      o[0] = mean[0] + cc[0] * ep.x;
      o[1] = mean[1] + cc[1] * ep.y;
      o[2] = mean[2] + cc[2] * ep.z;
      o[3] = mean[3] + cc[3] * ep.w;
      short4 sh, sl;
      unsigned short hh, ll;
      splitbf(o[0], hh, ll); sh.x = (short)hh; sl.x = (short)ll;
      splitbf(o[1], hh, ll); sh.y = (short)hh; sl.y = (short)ll;
      splitbf(o[2], hh, ll); sh.z = (short)hh; sl.z = (short)ll;
      splitbf(o[3], hh, ll); sh.w = (short)hh; sl.w = (short)ll;
      const size_t obase = (((size_t)(b * 2 + s2) * 512 + l) * 512) + h * 64 + tn;
      *(short4*)(smph + obase) = sh;
      *(short4*)(smpl + obase) = sl;
    }
  }
}

// ---------- gemm1_mfma: out = samples @ W_O^T + bias ----------
__global__ __launch_bounds__(256) void gemm1_mfma(const unsigned short* __restrict__ smph,
                                                  const unsigned short* __restrict__ smpl,
                                                  const unsigned short* __restrict__ woh,
                                                  const unsigned short* __restrict__ wol,
                                                  const float* __restrict__ bias,
                                                  float* __restrict__ out) {
  const int r0 = blockIdx.x * 64;
  const int n0 = blockIdx.y * 64;
  const int t = threadIdx.x;
  const int wv = t >> 6;
  const int lane = t & 63;
  const int lr = lane & 15;
  const int kq = lane >> 4;
  const size_t arow = ((size_t)(r0 + wv * 16 + lr)) * 512;
  f32x4 acc[4];
#pragma unroll
  for (int ns = 0; ns < 4; ++ns) acc[ns] = (f32x4){0.f, 0.f, 0.f, 0.f};
  for (int ks = 0; ks < 16; ++ks) {
    const int kb = ks * 32 + kq * 8;
    bf16x8 ah = *(const bf16x8*)(smph + arow + kb);
    bf16x8 al = *(const bf16x8*)(smpl + arow + kb);
#pragma unroll
    for (int ns = 0; ns < 4; ++ns) {
      const size_t brow = ((size_t)(n0 + ns * 16 + lr)) * 512 + kb;
      bf16x8 bh8 = *(const bf16x8*)(woh + brow);
      bf16x8 bl8 = *(const bf16x8*)(wol + brow);
      acc[ns] = __builtin_amdgcn_mfma_f32_16x16x32_bf16(ah, bh8, acc[ns], 0, 0, 0);
      acc[ns] = __builtin_amdgcn_mfma_f32_16x16x32_bf16(ah, bl8, acc[ns], 0, 0, 0);
      acc[ns] = __builtin_amdgcn_mfma_f32_16x16x32_bf16(al, bh8, acc[ns], 0, 0, 0);
    }
  }
#pragma unroll
  for (int ns = 0; ns < 4; ++ns) {
    const int outc = n0 + ns * 16 + lr;
    const float bc = bias[outc];
    const int rbase = r0 + wv * 16 + kq * 4;
#pragma unroll
    for (int r = 0; r < 4; ++r) {
      out[(size_t)(rbase + r) * 512 + outc] = acc[ns][r] + bc;
    }
  }
}

// ---------- kfin ----------
__global__ void kfin(const double* __restrict__ klbuf, float* __restrict__ dout) {
  if (threadIdx.x == 0 && blockIdx.x == 0) {
    double pb = 0.0;
    for (int b = 0; b < 8; ++b) pb += klbuf[3 + b] - klbuf[11 + b];
    double kl = -16384.0 + klbuf[0] + klbuf[1] - klbuf[2] + pb / 16.0;
    dout[4194304] = (float)kl;
  }
}

extern "C" void kernel_launch(void* const* d_in, const int* in_sizes, int n_in,
                              void* d_out, int out_size, void* d_ws, size_t ws_size,
                              hipStream_t stream) {
  (void)in_sizes; (void)n_in; (void)out_size; (void)ws_size;
  const float* x     = (const float*)d_in[0];
  const float* cur_k = (const float*)d_in[1];
  const float* eps   = (const float*)d_in[2];
  const float* W_qkv = (const float*)d_in[3];
  const float* lsf   = (const float*)d_in[4];
  const float* lls   = (const float*)d_in[5];
  const float* vind  = (const float*)d_in[6];
  const float* ltri  = (const float*)d_in[7];
  const float* ldia  = (const float*)d_in[8];
  const float* Wo    = (const float*)d_in[9];
  const float* Wob   = (const float*)d_in[10];
  float* out = (float*)d_out;
  float* ws = (float*)d_ws;
  float* qs   = ws + OFF_QS;
  float* vg   = ws + OFF_VG;
  float* qn   = ws + OFF_QN;
  float* kbs  = ws + OFF_KBS;
  float* kbn  = ws + OFF_KBN;
  float* linv = ws + OFF_LINV;
  float* v1   = ws + OFF_V1;
  float* v1s  = ws + OFF_V1SQ;
  float* mean = ws + OFF_MEAN;
  float* v2   = ws + OFF_V2;
  float* kkk  = ws + OFF_KKK;
  float* v3   = ws + OFF_V3;
  unsigned short* v1h = (unsigned short*)(ws + OFF_V1H);
  unsigned short* sth = (unsigned short*)(ws + OFF_STH);
  unsigned short* woh = (unsigned short*)(ws + OFF_WOH);
  unsigned short* wol = (unsigned short*)(ws + OFF_WOL);
  unsigned short* smph = (unsigned short*)(ws + OFF_QS);  // reuse qs (dead after k6)
  unsigned short* smpl = (unsigned short*)(ws + OFF_VG);  // reuse vg (dead after k6)
  double* kld = (double*)(ws + OFF_KLD);

  hipMemsetAsync(kld, 0, 32 * sizeof(double), stream);
  gemm0<<<dim3(64, 16), 256, 0, stream>>>(x, W_qkv, qs, vg, lls, qn);
  k2_kbeta<<<512, 256, 0, stream>>>(W_qkv, cur_k, lls, kbs, kbn);
  k3a_build<<<8, 256, 0, stream>>>(kbs, kbn, vind, lsf, kkk, kld);
  k3b_cholinv<<<8, 64, 0, stream>>>(kkk, linv);
  ks_build<<<512, 256, 0, stream>>>(ltri, ldia, sth, kld);
  kconv_wo<<<1024, 256, 0, stream>>>(Wo, woh, wol);
  k4_fused<<<dim3(8, 64), 256, 73984, stream>>>(qs, qn, kbs, kbn, linv, vind, lsf,
                                                v1, v1h, v1s, mean);
  k5_v2<<<64, 256, 0, stream>>>(v1, vg, v2, kld);
  k6_mean1<<<dim3(8, 64), 256, 69632, stream>>>(qs, qn, vg, lsf, mean, kld);
  k10_mfma<<<dim3(64, 4, 4), 256, 0, stream>>>(v1h, sth, v3);
  k8_samples<<<dim3(8, 64), 256, 52224, stream>>>(v1, v2, mean, v3, v1s, eps, lsf,
                                                  smph, smpl);
  gemm1_mfma<<<dim3(128, 8), 256, 0, stream>>>(smph, smpl, woh, wol, Wob, out);
  kfin<<<1, 64, 0, stream>>>(kld, out);
}